// Round 5
// baseline (404.619 us; speedup 1.0000x reference)
//
#include <hip/hip_runtime.h>
#include <math.h>

#define NN 1024
#define DD 128
#define HH 8

typedef __attribute__((ext_vector_type(8))) short short8;
typedef __attribute__((ext_vector_type(4))) float f32x4;

__device__ inline unsigned short f2bf(float x) {
    union { float f; unsigned u; } v; v.f = x;
    return (unsigned short)((v.u + 0x7FFF + ((v.u >> 16) & 1)) >> 16);
}
__device__ inline unsigned pack2(float a, float b) {
    return (unsigned)f2bf(a) | ((unsigned)f2bf(b) << 16);
}

// ---------------- weight prep: transpose fp32 [R][C] -> bf16 [C][R] ----------
__global__ __launch_bounds__(256) void k_prep_w(
    const float* __restrict__ Wq, const float* __restrict__ Wk, const float* __restrict__ Wv,
    const float* __restrict__ Wo, const float* __restrict__ Wg,
    unsigned short* WqT, unsigned short* WkT, unsigned short* WvT,
    unsigned short* WoT, unsigned short* WgT) {
    int id = blockIdx.x;
    const float* src; unsigned short* dst; int R, C, ti;
    if (id < 128)      { src = Wq; dst = WqT; R = 128;  C = 1024; ti = id; }
    else if (id < 256) { src = Wk; dst = WkT; R = 128;  C = 1024; ti = id - 128; }
    else if (id < 384) { src = Wv; dst = WvT; R = 128;  C = 1024; ti = id - 256; }
    else if (id < 512) { src = Wo; dst = WoT; R = 1024; C = 128;  ti = id - 384; }
    else               { src = Wg; dst = WgT; R = 128;  C = 128;  ti = id - 512; }
    int tc = C >> 5;
    int r0 = (ti / tc) << 5, c0 = (ti % tc) << 5;
    __shared__ float T[32][33];
    int tid = threadIdx.x;
    int r = tid >> 3, c4 = (tid & 7) << 2;
    float4 v = *(const float4*)&src[(size_t)(r0 + r) * C + c0 + c4];
    T[r][c4] = v.x; T[r][c4 + 1] = v.y; T[r][c4 + 2] = v.z; T[r][c4 + 3] = v.w;
    __syncthreads();
    int c = tid >> 3, r4 = (tid & 7) << 2;
    uint2 o;
    o.x = pack2(T[r4][c], T[r4 + 1][c]);
    o.y = pack2(T[r4 + 2][c], T[r4 + 3][c]);
    *(uint2*)&dst[(size_t)(c0 + c) * R + r0 + r4] = o;
}

// ---------------- K1: c = bf16(F_c + emb) ------------------------------------
__global__ __launch_bounds__(256) void k_embed(const float* __restrict__ F_c,
                                               const int* __restrict__ t,
                                               unsigned short* __restrict__ cb) {
    int gi = blockIdx.x * 256 + threadIdx.x;    // 262144 chunks of 8
    int row = gi >> 4, ch = gi & 15;
    int b = row >> 10, n = row & 1023;
    float tv = (float)t[b];
    int j = n & 511;
    float e = tv * expf(-(float)j * 0.013518112092919054f);
    float emb = (n < 512) ? sinf(e) : cosf(e);
    const float* src = F_c + (size_t)row * 128 + ch * 8;
    float4 a = *(const float4*)src;
    float4 c4 = *(const float4*)(src + 4);
    uint4 o;
    o.x = pack2(a.x + emb, a.y + emb);  o.y = pack2(a.z + emb, a.w + emb);
    o.z = pack2(c4.x + emb, c4.y + emb); o.w = pack2(c4.z + emb, c4.w + emb);
    *(uint4*)&cb[(size_t)row * 128 + ch * 8] = o;
}

// ---------------- shared GEMM body for the projection kernels ----------------
__device__ __forceinline__ void proj_body(const unsigned short* __restrict__ Ain,
                                          const unsigned short* __restrict__ WT,
                                          const float* __restrict__ bias,
                                          unsigned short* __restrict__ Out,
                                          float scale, int mode, int bh_mul,
                                          unsigned short* sm, int head, int m0) {
    unsigned short* CT  = sm;               // [128][136]
    unsigned short* WTs = sm + 128 * 136;   // [128][136]
    int tid = threadIdx.x;
    int w = tid >> 6, lane = tid & 63, n16 = lane & 15, quad = lane >> 4;
#pragma unroll
    for (int p = 0; p < 8; ++p) {
        int idx = tid + p * 256;
        int r = idx >> 4, ch = idx & 15;
        *(uint4*)&CT[r * 136 + ch * 8]  = *(const uint4*)&Ain[(size_t)(m0 + r) * 128 + ch * 8];
        *(uint4*)&WTs[r * 136 + ch * 8] = *(const uint4*)&WT[(size_t)(head * 128 + r) * 128 + ch * 8];
    }
    __syncthreads();
    int wr = (w >> 1) * 64, wc = (w & 1) * 64;
    f32x4 acc[4][4];
#pragma unroll
    for (int i = 0; i < 4; i++)
#pragma unroll
        for (int j = 0; j < 4; j++) acc[i][j] = (f32x4){0.f, 0.f, 0.f, 0.f};
#pragma unroll
    for (int kk = 0; kk < 4; ++kk) {
        short8 af[4], bf[4];
#pragma unroll
        for (int rb = 0; rb < 4; ++rb)
            af[rb] = *(const short8*)&CT[(wr + rb * 16 + n16) * 136 + kk * 32 + quad * 8];
#pragma unroll
        for (int cb = 0; cb < 4; ++cb)
            bf[cb] = *(const short8*)&WTs[(wc + cb * 16 + n16) * 136 + kk * 32 + quad * 8];
#pragma unroll
        for (int rb = 0; rb < 4; ++rb)
#pragma unroll
            for (int cb = 0; cb < 4; ++cb)
                acc[rb][cb] = __builtin_amdgcn_mfma_f32_16x16x32_bf16(af[rb], bf[cb], acc[rb][cb], 0, 0, 0);
    }
    __syncthreads();    // all frag reads done; reuse CT as bounce
#pragma unroll
    for (int rb = 0; rb < 4; ++rb)
#pragma unroll
        for (int cb = 0; cb < 4; ++cb) {
            int colb = wc + cb * 16 + n16;
            float bs = bias ? bias[head * 128 + colb] : 0.f;
#pragma unroll
            for (int reg = 0; reg < 4; ++reg) {
                int rowb = wr + rb * 16 + quad * 4 + reg;
                unsigned short val = f2bf((acc[rb][cb][reg] + bs) * scale);
                if (mode == 0) CT[rowb * 136 + colb] = val;
                else           CT[colb * 136 + rowb] = val;
            }
        }
    __syncthreads();
    int b = m0 >> 10, n0 = m0 & 1023;
    size_t base = (size_t)(b * bh_mul + head) * 131072;
    if (mode == 0) {
#pragma unroll
        for (int p = 0; p < 8; ++p) {
            int idx = tid + p * 256;
            int r = idx >> 4, ch = idx & 15;
            *(uint4*)&Out[base + (size_t)(n0 + r) * 128 + ch * 8] = *(const uint4*)&CT[r * 136 + ch * 8];
        }
    } else {
#pragma unroll
        for (int p = 0; p < 8; ++p) {
            int idx = tid + p * 256;
            int r = idx >> 4, ch = idx & 15;    // r = out-col row (d), ch over the 128 n's
            *(uint4*)&Out[base + (size_t)r * 1024 + n0 + ch * 8] = *(const uint4*)&CT[r * 136 + ch * 8];
        }
    }
}

// ---------------- K2: fused Q/K/V projections (blockIdx.z selects) -----------
__global__ __launch_bounds__(256) void k_proj_qkv(const unsigned short* __restrict__ Ain,
                                                  const unsigned short* __restrict__ W0,
                                                  const unsigned short* __restrict__ W1,
                                                  const unsigned short* __restrict__ W2,
                                                  const float* __restrict__ b0,
                                                  const float* __restrict__ b1,
                                                  const float* __restrict__ b2,
                                                  unsigned short* __restrict__ O0,
                                                  unsigned short* __restrict__ O1,
                                                  unsigned short* __restrict__ O2,
                                                  float qscale) {
    __shared__ __align__(16) unsigned short sm[2 * 128 * 136];
    int z = blockIdx.z;
    const unsigned short* WT = (z == 0) ? W0 : (z == 1) ? W1 : W2;
    const float* bias = (z == 0) ? b0 : (z == 1) ? b1 : b2;
    unsigned short* Out = (z == 0) ? O0 : (z == 1) ? O1 : O2;
    float scale = (z == 0) ? qscale : 1.f;
    int mode = (z == 2) ? 1 : 0;
    proj_body(Ain, WT, bias, Out, scale, mode, 8, sm, blockIdx.y, blockIdx.x * 128);
}

// ---------------- generic K=128 MFMA GEMM (kept for hgT) ---------------------
__global__ __launch_bounds__(256) void k_proj(const unsigned short* __restrict__ Ain,
                                              const unsigned short* __restrict__ WT,
                                              const float* __restrict__ bias,
                                              unsigned short* __restrict__ Out,
                                              float scale, int mode, int bh_mul) {
    __shared__ __align__(16) unsigned short sm[2 * 128 * 136];
    proj_body(Ain, WT, bias, Out, scale, mode, bh_mul, sm, blockIdx.y, blockIdx.x * 128);
}

// ---------------- K3 attention: compute one 64-key tile ----------------------
__device__ __forceinline__ void attn_compute(const unsigned short* __restrict__ Ksc,
                                             const unsigned short* __restrict__ Vtc,
                                             const short8 (&qf)[2][4],
                                             float (&mrun)[2], float (&lrun)[2],
                                             f32x4 (&O)[2][8], int n16, int quad) {
    // S^T = K Q^T : rows = keys (quad*4+reg within 16-block kb), cols = q (n16)
    f32x4 S[2][4];
#pragma unroll
    for (int qb2 = 0; qb2 < 2; ++qb2)
#pragma unroll
        for (int kb = 0; kb < 4; ++kb) S[qb2][kb] = (f32x4){0.f, 0.f, 0.f, 0.f};
    __builtin_amdgcn_s_setprio(1);
#pragma unroll
    for (int kb = 0; kb < 4; ++kb)
#pragma unroll
        for (int dc = 0; dc < 4; ++dc) {
            short8 kf = *(const short8*)&Ksc[(kb * 16 + n16) * 136 + dc * 32 + quad * 8];
            S[0][kb] = __builtin_amdgcn_mfma_f32_16x16x32_bf16(kf, qf[0][dc], S[0][kb], 0, 0, 0);
            S[1][kb] = __builtin_amdgcn_mfma_f32_16x16x32_bf16(kf, qf[1][dc], S[1][kb], 0, 0, 0);
        }
    __builtin_amdgcn_s_setprio(0);

    // per-q max: local over 16 regs, then across the 4 quads (2 shuffles)
    float mx[2];
#pragma unroll
    for (int qb2 = 0; qb2 < 2; ++qb2) {
        float m = S[qb2][0][0];
#pragma unroll
        for (int kb = 0; kb < 4; ++kb)
#pragma unroll
            for (int reg = 0; reg < 4; ++reg) m = fmaxf(m, S[qb2][kb][reg]);
        m = fmaxf(m, __shfl_xor(m, 16));
        m = fmaxf(m, __shfl_xor(m, 32));
        mx[qb2] = m;
    }
    // defer-max: skip O-rescale when max grew by <= 1 (P bounded by e)
    int keep = (mx[0] - mrun[0] <= 1.f) && (mx[1] - mrun[1] <= 1.f);
    if (!__all(keep)) {
        float mn0 = fmaxf(mrun[0], mx[0]);
        float mn1 = fmaxf(mrun[1], mx[1]);
        float a0 = __expf(mrun[0] - mn0);
        float a1 = __expf(mrun[1] - mn1);
        mrun[0] = mn0; mrun[1] = mn1;
        lrun[0] *= a0; lrun[1] *= a1;
        float av0[4], av1[4];
#pragma unroll
        for (int reg = 0; reg < 4; ++reg) {
            av0[reg] = __shfl(a0, quad * 4 + reg);
            av1[reg] = __shfl(a1, quad * 4 + reg);
        }
#pragma unroll
        for (int dc = 0; dc < 8; ++dc)
#pragma unroll
            for (int reg = 0; reg < 4; ++reg) {
                O[0][dc][reg] *= av0[reg];
                O[1][dc][reg] *= av1[reg];
            }
    }
    // P = exp(S - m), row-sum (2 shuffles), all lane-local
#pragma unroll
    for (int qb2 = 0; qb2 < 2; ++qb2) {
        float ps = 0.f;
#pragma unroll
        for (int kb = 0; kb < 4; ++kb)
#pragma unroll
            for (int reg = 0; reg < 4; ++reg) {
                float p = __expf(S[qb2][kb][reg] - mrun[qb2]);
                S[qb2][kb][reg] = p;
                ps += p;
            }
        ps += __shfl_xor(ps, 16);
        ps += __shfl_xor(ps, 32);
        lrun[qb2] += ps;
    }
    // pack P to bf16 pairs in-register (A-operand dwords)
    unsigned pk01[2][4], pk23[2][4];
#pragma unroll
    for (int qb2 = 0; qb2 < 2; ++qb2)
#pragma unroll
        for (int kb = 0; kb < 4; ++kb) {
            asm("v_cvt_pk_bf16_f32 %0, %1, %2"
                : "=v"(pk01[qb2][kb]) : "v"(S[qb2][kb][0]), "v"(S[qb2][kb][1]));
            asm("v_cvt_pk_bf16_f32 %0, %1, %2"
                : "=v"(pk23[qb2][kb]) : "v"(S[qb2][kb][2]), "v"(S[qb2][kb][3]));
        }
    // O += P V  (B-operand read from permuted Vt matches P's k-slot order)
    __builtin_amdgcn_s_setprio(1);
#pragma unroll
    for (int c = 0; c < 2; ++c) {
        union { uint4 u; short8 s; } pa0, pa1;
        pa0.u = make_uint4(pk01[0][2 * c], pk23[0][2 * c], pk01[0][2 * c + 1], pk23[0][2 * c + 1]);
        pa1.u = make_uint4(pk01[1][2 * c], pk23[1][2 * c], pk01[1][2 * c + 1], pk23[1][2 * c + 1]);
#pragma unroll
        for (int dc = 0; dc < 8; ++dc) {
            short8 vf = *(const short8*)&Vtc[(dc * 16 + n16) * 72 + c * 32 + quad * 8];
            O[0][dc] = __builtin_amdgcn_mfma_f32_16x16x32_bf16(pa0.s, vf, O[0][dc], 0, 0, 0);
            O[1][dc] = __builtin_amdgcn_mfma_f32_16x16x32_bf16(pa1.s, vf, O[1][dc], 0, 0, 0);
        }
    }
    __builtin_amdgcn_s_setprio(0);
}

// one pipeline step: loads tile kt+2 into (LK,LV); stages tile kt+1 from (WK,WV)
// into buf[(kt+1)&1]; computes tile kt from buf[kt&1]; one barrier.
__device__ __forceinline__ void attn_step(int kt,
                                          const unsigned short* __restrict__ Kp,
                                          const unsigned short* __restrict__ Vp,
                                          unsigned short* sm, int tid, int vr0, int k0, int slotA,
                                          uint4 (&LK)[4], uint4 (&LV)[4],
                                          uint4 (&WK)[4], uint4 (&WV)[4],
                                          const short8 (&qf)[2][4],
                                          float (&mrun)[2], float (&lrun)[2],
                                          f32x4 (&O)[2][8], int n16, int quad) {
    // 1. issue loads for tile kt+2 FIRST (counted-vmcnt: later ds_writes of WK/WV
    //    wait only on WK/WV's loads, which completed before the last barrier)
    if (kt + 2 < 16) {
#pragma unroll
        for (int p = 0; p < 4; ++p) {
            int idx = tid + p * 256;
            int r = idx >> 4, ch = idx & 15;
            LK[p] = *(const uint4*)&Kp[(size_t)((kt + 2) * 64 + r) * 128 + ch * 8];
            LV[p] = *(const uint4*)&Vp[(size_t)(vr0 + p * 32) * 1024 + (kt + 2) * 64 + k0];
        }
    }
    // 2. stage tile kt+1 into the other buffer; drains under this tile's MFMA
    if (kt + 1 < 16) {
        unsigned short* Kw = sm + ((kt + 1) & 1) * 17920;
        unsigned short* Vw = Kw + 8704;
#pragma unroll
        for (int p = 0; p < 4; ++p) {
            int idx = tid + p * 256;
            int r = idx >> 4, ch = idx & 15;
            *(uint4*)&Kw[r * 136 + ch * 8] = WK[p];
        }
#pragma unroll
        for (int p = 0; p < 4; ++p) {
            int r = vr0 + p * 32;
            *(uint2*)&Vw[r * 72 + slotA]     = make_uint2(WV[p].x, WV[p].y);
            *(uint2*)&Vw[r * 72 + slotA + 8] = make_uint2(WV[p].z, WV[p].w);
        }
    }
    // 3. compute current tile
    {
        const unsigned short* Ksc = sm + (kt & 1) * 17920;
        const unsigned short* Vtc = Ksc + 8704;
        attn_compute(Ksc, Vtc, qf, mrun, lrun, O, n16, quad);
    }
    // 4. single barrier: buf[(kt+1)&1] writes visible; buf[kt&1] reads done
    __syncthreads();
}

// ---------------- K3: MFMA flash attention, dbuf LDS, 1 barrier/tile ---------
__global__ __launch_bounds__(256, 2) void k_attn2(const unsigned short* __restrict__ qbuf,
                                                  const unsigned short* __restrict__ kbuf,
                                                  const unsigned short* __restrict__ vtb,
                                                  unsigned short* __restrict__ ctxb) {
    __shared__ __align__(16) unsigned short sm[35840];   // 2 x (Ks[64][136] + Vt[128][72]) = 71680 B
    const int tid = threadIdx.x;
    const int w = tid >> 6, lane = tid & 63;
    const int n16 = lane & 15, quad = lane >> 4;
    const int g = blockIdx.x;
    const int bh = g & 127, tileq = g >> 7;   // bh-major: a (b,h)'s 8 q-tiles share an XCD

    const unsigned short* Qp = qbuf + (size_t)bh * 131072 + (size_t)tileq * 16384;
    const unsigned short* Kp = kbuf + (size_t)bh * 131072;
    const unsigned short* Vp = vtb + (size_t)bh * 131072;

    // Q fragments (B-operand layout: row=n16=q, k=quad*8+j)
    short8 qf[2][4];
#pragma unroll
    for (int qb2 = 0; qb2 < 2; ++qb2)
#pragma unroll
        for (int dc = 0; dc < 4; ++dc)
            qf[qb2][dc] = *(const short8*)&Qp[(size_t)(w * 32 + qb2 * 16 + n16) * 128 + dc * 32 + quad * 8];

    float mrun[2] = {-1e30f, -1e30f};
    float lrun[2] = {0.f, 0.f};
    f32x4 O[2][8];
#pragma unroll
    for (int qb2 = 0; qb2 < 2; ++qb2)
#pragma unroll
        for (int dc = 0; dc < 8; ++dc) O[qb2][dc] = (f32x4){0.f, 0.f, 0.f, 0.f};

    // staging geometry
    const int vr0 = tid >> 3;                          // V: row, +32 per p
    const int k0 = (tid & 7) * 8;
    const int slotA = ((k0 >> 5) << 5) | (((k0 >> 2) & 3) << 3) | (((k0 >> 4) & 1) << 2);

    // two staging register sets: tile t lives in set (t&1)
    uint4 ka[4], va[4], kb4[4], vb4[4];
#pragma unroll
    for (int p = 0; p < 4; ++p) {
        int idx = tid + p * 256;
        int r = idx >> 4, ch = idx & 15;
        ka[p]  = *(const uint4*)&Kp[(size_t)r * 128 + ch * 8];
        va[p]  = *(const uint4*)&Vp[(size_t)(vr0 + p * 32) * 1024 + k0];
        kb4[p] = *(const uint4*)&Kp[(size_t)(64 + r) * 128 + ch * 8];
        vb4[p] = *(const uint4*)&Vp[(size_t)(vr0 + p * 32) * 1024 + 64 + k0];
    }
    // stage tile 0 into buf0
    {
        unsigned short* Kw = sm;
        unsigned short* Vw = sm + 8704;
#pragma unroll
        for (int p = 0; p < 4; ++p) {
            int idx = tid + p * 256;
            int r = idx >> 4, ch = idx & 15;
            *(uint4*)&Kw[r * 136 + ch * 8] = ka[p];
        }
#pragma unroll
        for (int p = 0; p < 4; ++p) {
            int r = vr0 + p * 32;
            *(uint2*)&Vw[r * 72 + slotA]     = make_uint2(va[p].x, va[p].y);
            *(uint2*)&Vw[r * 72 + slotA + 8] = make_uint2(va[p].z, va[p].w);
        }
    }
    __syncthreads();

    for (int t = 0; t < 8; ++t) {
        int kt0 = 2 * t, kt1 = 2 * t + 1;
        attn_step(kt0, Kp, Vp, sm, tid, vr0, k0, slotA, ka, va, kb4, vb4,
                  qf, mrun, lrun, O, n16, quad);
        attn_step(kt1, Kp, Vp, sm, tid, vr0, k0, slotA, kb4, vb4, ka, va,
                  qf, mrun, lrun, O, n16, quad);
    }

    // epilogue: 1/l lives at q=n16, O rows at q=quad*4+reg -> redistribute once
    float lv[2][4];
#pragma unroll
    for (int qb2 = 0; qb2 < 2; ++qb2)
#pragma unroll
        for (int reg = 0; reg < 4; ++reg)
            lv[qb2][reg] = 1.f / __shfl(lrun[qb2], quad * 4 + reg);
    unsigned short* Ct = sm;    // bounce [128][136] rows of this block's 128 q
#pragma unroll
    for (int qb2 = 0; qb2 < 2; ++qb2)
#pragma unroll
        for (int reg = 0; reg < 4; ++reg) {
            int row = w * 32 + qb2 * 16 + quad * 4 + reg;
#pragma unroll
            for (int dc = 0; dc < 8; ++dc)
                Ct[row * 136 + dc * 16 + n16] = f2bf(O[qb2][dc][reg] * lv[qb2][reg]);
        }
    __syncthreads();
    unsigned short* Outp = ctxb + (size_t)bh * 131072 + (size_t)tileq * 16384;
#pragma unroll
    for (int p = 0; p < 8; ++p) {
        int idx = tid + p * 256;
        int r = idx >> 4, ch = idx & 15;
        *(uint4*)&Outp[(size_t)r * 128 + ch * 8] = *(const uint4*)&Ct[r * 136 + ch * 8];
    }
}

// ---------------- K4: h = ctx @ Wo + bo (M=16384, K=1024, N=128) -------------
__global__ __launch_bounds__(256) void k_proj_o(const unsigned short* __restrict__ Ctxb,
                                                const unsigned short* __restrict__ WoT,
                                                const float* __restrict__ bo,
                                                unsigned short* __restrict__ Hb) {
    __shared__ __align__(16) unsigned short sm[64 * 72 + 128 * 72];
    unsigned short* As = sm;            // [64][72]
    unsigned short* Bs = sm + 64 * 72;  // [128][72]
    int tid = threadIdx.x;
    int m0 = blockIdx.x * 64;
    int b = m0 >> 10, n0 = m0 & 1023;
    int w = tid >> 6, lane = tid & 63, n16 = lane & 15, quad = lane >> 4;
    int wr = (w & 1) * 32, wc = (w >> 1) * 64;
    f32x4 acc[2][4];
#pragma unroll
    for (int i = 0; i < 2; i++)
#pragma unroll
        for (int j = 0; j < 4; j++) acc[i][j] = (f32x4){0.f, 0.f, 0.f, 0.f};
    for (int kt = 0; kt < 16; ++kt) {
        __syncthreads();
        int hh = kt >> 1, d0 = (kt & 1) * 64;
#pragma unroll
        for (int p = 0; p < 2; ++p) {
            int idx = tid + p * 256;
            int r = idx >> 3, ch = idx & 7;
            *(uint4*)&As[r * 72 + ch * 8] =
                *(const uint4*)&Ctxb[((size_t)(b * 8 + hh) * 1024 + n0 + r) * 128 + d0 + ch * 8];
        }
#pragma unroll
        for (int p = 0; p < 4; ++p) {
            int idx = tid + p * 256;
            int r = idx >> 3, ch = idx & 7;
            *(uint4*)&Bs[r * 72 + ch * 8] = *(const uint4*)&WoT[(size_t)r * 1024 + kt * 64 + ch * 8];
        }
        __syncthreads();
#pragma unroll
        for (int kk = 0; kk < 2; ++kk) {
            short8 af0 = *(const short8*)&As[(wr + n16) * 72 + kk * 32 + quad * 8];
            short8 af1 = *(const short8*)&As[(wr + 16 + n16) * 72 + kk * 32 + quad * 8];
#pragma unroll
            for (int cb = 0; cb < 4; ++cb) {
                short8 bf = *(const short8*)&Bs[(wc + cb * 16 + n16) * 72 + kk * 32 + quad * 8];
                acc[0][cb] = __builtin_amdgcn_mfma_f32_16x16x32_bf16(af0, bf, acc[0][cb], 0, 0, 0);
                acc[1][cb] = __builtin_amdgcn_mfma_f32_16x16x32_bf16(af1, bf, acc[1][cb], 0, 0, 0);
            }
        }
    }
    __syncthreads();
    unsigned short* Ct = sm;    // bounce [64][136] (8704 <= 13824)
#pragma unroll
    for (int rb = 0; rb < 2; ++rb)
#pragma unroll
        for (int cb = 0; cb < 4; ++cb) {
            int col = wc + cb * 16 + n16;
            float bs = bo[col];
#pragma unroll
            for (int reg = 0; reg < 4; ++reg)
                Ct[(wr + rb * 16 + quad * 4 + reg) * 136 + col] = f2bf(acc[rb][cb][reg] + bs);
        }
    __syncthreads();
#pragma unroll
    for (int p = 0; p < 4; ++p) {
        int idx = tid + p * 256;
        int r = idx >> 4, ch = idx & 15;
        *(uint4*)&Hb[(size_t)(m0 + r) * 128 + ch * 8] = *(const uint4*)&Ct[r * 136 + ch * 8];
    }
}

// ---------------- K6: feat = relu(A_t @ hg), A_t fp32 cast inline ------------
__global__ __launch_bounds__(256) void k_at_gemm(const float* __restrict__ At,
                                                 const unsigned short* __restrict__ HgT,
                                                 float* __restrict__ Feat) {
    __shared__ __align__(16) unsigned short sm[64 * 72 + 128 * 72];
    unsigned short* As = sm;
    unsigned short* Bs = sm + 64 * 72;
    int tid = threadIdx.x;
    int bz = blockIdx.z;
    int m0 = blockIdx.x * 64;
    int w = tid >> 6, lane = tid & 63, n16 = lane & 15, quad = lane >> 4;
    int wr = (w & 1) * 32, wc = (w >> 1) * 64;
    f32x4 acc[2][4];
#pragma unroll
    for (int i = 0; i < 2; i++)
#pragma unroll
        for (int j = 0; j < 4; j++) acc[i][j] = (f32x4){0.f, 0.f, 0.f, 0.f};
    for (int kt = 0; kt < 16; ++kt) {
        __syncthreads();
#pragma unroll
        for (int p = 0; p < 2; ++p) {
            int idx = tid + p * 256;
            int r = idx >> 3, ch = idx & 7;
            const float* s = At + (size_t)bz * 1048576 + (size_t)(m0 + r) * 1024 + kt * 64 + ch * 8;
            float4 x = *(const float4*)s;
            float4 y = *(const float4*)(s + 4);
            uint4 o;
            o.x = pack2(x.x, x.y); o.y = pack2(x.z, x.w);
            o.z = pack2(y.x, y.y); o.w = pack2(y.z, y.w);
            *(uint4*)&As[r * 72 + ch * 8] = o;
        }
#pragma unroll
        for (int p = 0; p < 4; ++p) {
            int idx = tid + p * 256;
            int r = idx >> 3, ch = idx & 7;
            *(uint4*)&Bs[r * 72 + ch * 8] =
                *(const uint4*)&HgT[(size_t)bz * 131072 + (size_t)r * 1024 + kt * 64 + ch * 8];
        }
        __syncthreads();
#pragma unroll
        for (int kk = 0; kk < 2; ++kk) {
            short8 af0 = *(const short8*)&As[(wr + n16) * 72 + kk * 32 + quad * 8];
            short8 af1 = *(const short8*)&As[(wr + 16 + n16) * 72 + kk * 32 + quad * 8];
#pragma unroll
            for (int cb = 0; cb < 4; ++cb) {
                short8 bf = *(const short8*)&Bs[(wc + cb * 16 + n16) * 72 + kk * 32 + quad * 8];
                acc[0][cb] = __builtin_amdgcn_mfma_f32_16x16x32_bf16(af0, bf, acc[0][cb], 0, 0, 0);
                acc[1][cb] = __builtin_amdgcn_mfma_f32_16x16x32_bf16(af1, bf, acc[1][cb], 0, 0, 0);
            }
        }
    }
#pragma unroll
    for (int rb = 0; rb < 2; ++rb)
#pragma unroll
        for (int cb = 0; cb < 4; ++cb) {
            int col = wc + cb * 16 + n16;
#pragma unroll
            for (int reg = 0; reg < 4; ++reg) {
                int row = m0 + wr + rb * 16 + quad * 4 + reg;
                Feat[(size_t)bz * 131072 + (size_t)row * 128 + col] = fmaxf(acc[rb][cb][reg], 0.f);
            }
        }
}

// ---------------- K7: row normalize fp32 -> bf16 ------------------------------
__global__ __launch_bounds__(64) void k_norm(const float* __restrict__ F,
                                             unsigned short* __restrict__ Nb) {
    int row = blockIdx.x, tdx = threadIdx.x;
    const float* p = F + (size_t)row * 128;
    float2 xy = *(const float2*)&p[tdx * 2];
    float sum = xy.x + xy.y;
#pragma unroll
    for (int off = 32; off; off >>= 1) sum += __shfl_xor(sum, off);
    float mu = sum * (1.f / 128.f);
    float d0 = xy.x - mu, d1 = xy.y - mu;
    float sq = d0 * d0 + d1 * d1;
#pragma unroll
    for (int off = 32; off; off >>= 1) sq += __shfl_xor(sq, off);
    float sd = sqrtf(sq * (1.f / 127.f));
    float inv = 1.f / (sd + 1e-8f);
    ((unsigned*)Nb)[(size_t)row * 64 + tdx] = pack2(d0 * inv, d1 * inv);
}

// ---------------- K8: out[b] = norm @ norm^T / 128 (bf16 MFMA) ----------------
__global__ __launch_bounds__(256) void k_corr(const unsigned short* __restrict__ Nb,
                                              float* __restrict__ Out) {
    __shared__ __align__(16) unsigned short sm[2 * 128 * 136];
    unsigned short* Ar = sm;
    unsigned short* Br = sm + 128 * 136;
    int tid = threadIdx.x;
    int bz = blockIdx.z;
    int n0 = blockIdx.x * 128, m0 = blockIdx.y * 128;
    const unsigned short* base = Nb + (size_t)bz * 131072;
    int w = tid >> 6, lane = tid & 63, n16 = lane & 15, quad = lane >> 4;
#pragma unroll
    for (int p = 0; p < 8; ++p) {
        int idx = tid + p * 256;
        int r = idx >> 4, ch = idx & 15;
        *(uint4*)&Ar[r * 136 + ch * 8] = *(const uint4*)&base[(size_t)(n0 + r) * 128 + ch * 8];
        *(uint4*)&Br[r * 136 + ch * 8] = *(const uint4*)&base[(size_t)(m0 + r) * 128 + ch * 8];
    }
    __syncthreads();
    int wr = (w >> 1) * 64, wc = (w & 1) * 64;
    f32x4 acc[4][4];
#pragma unroll
    for (int i = 0; i < 4; i++)
#pragma unroll
        for (int j = 0; j < 4; j++) acc[i][j] = (f32x4){0.f, 0.f, 0.f, 0.f};
#pragma unroll
    for (int kk = 0; kk < 4; ++kk) {
        short8 af[4], bf[4];
#pragma unroll
        for (int rb = 0; rb < 4; ++rb)
            af[rb] = *(const short8*)&Ar[(wr + rb * 16 + n16) * 136 + kk * 32 + quad * 8];
#pragma unroll
        for (int cb = 0; cb < 4; ++cb)
            bf[cb] = *(const short8*)&Br[(wc + cb * 16 + n16) * 136 + kk * 32 + quad * 8];
#pragma unroll
        for (int rb = 0; rb < 4; ++rb)
#pragma unroll
            for (int cb = 0; cb < 4; ++cb)
                acc[rb][cb] = __builtin_amdgcn_mfma_f32_16x16x32_bf16(af[rb], bf[cb], acc[rb][cb], 0, 0, 0);
    }
#pragma unroll
    for (int rb = 0; rb < 4; ++rb)
#pragma unroll
        for (int cb = 0; cb < 4; ++cb)
#pragma unroll
            for (int reg = 0; reg < 4; ++reg) {
                int row = n0 + wr + rb * 16 + quad * 4 + reg;
                int col = m0 + wc + cb * 16 + n16;
                Out[(size_t)bz * 1048576 + (size_t)row * 1024 + col] = acc[rb][cb][reg] * 0.0078125f;
            }
}

extern "C" void kernel_launch(void* const* d_in, const int* in_sizes, int n_in,
                              void* d_out, int out_size, void* d_ws, size_t ws_size,
                              hipStream_t stream) {
    const float* A_t = (const float*)d_in[0];
    const float* F_c = (const float*)d_in[1];
    const int*   t   = (const int*)d_in[2];
    const float* Wq  = (const float*)d_in[3];
    const float* bq  = (const float*)d_in[4];
    const float* Wk  = (const float*)d_in[5];
    const float* bk  = (const float*)d_in[6];
    const float* Wv  = (const float*)d_in[7];
    const float* bv  = (const float*)d_in[8];
    const float* Wo  = (const float*)d_in[9];
    const float* bo  = (const float*)d_in[10];
    const float* Wg  = (const float*)d_in[11];
    float* out = (float*)d_out;
    char* ws = (char*)d_ws;

    unsigned short* cb   = (unsigned short*)(ws);                 //  4 MB
    unsigned short* qb   = (unsigned short*)(ws + 4194304);       // 33.5 MB
    unsigned short* kbuf = (unsigned short*)(ws + 37748736);
    unsigned short* vtb  = (unsigned short*)(ws + 71303168);
    unsigned short* ctxb = (unsigned short*)(ws + 104857600);
    unsigned short* hb   = (unsigned short*)(ws + 138412032);     //  4 MB
    unsigned short* hgT  = (unsigned short*)(ws + 142606336);     //  4 MB
    float*          feat = (float*)        (ws + 146800640);      //  8 MB
    unsigned short* nb   = (unsigned short*)(ws + 155189248);     //  4 MB
    unsigned short* WqT  = (unsigned short*)(ws + 159383552);
    unsigned short* WkT  = (unsigned short*)(ws + 159645696);
    unsigned short* WvT  = (unsigned short*)(ws + 159907840);
    unsigned short* WoT  = (unsigned short*)(ws + 160169984);
    unsigned short* WgT  = (unsigned short*)(ws + 160432128);

    const float qscale = 0.08838834764831845f;   // 1/sqrt(128)

    k_prep_w<<<528, 256, 0, stream>>>(Wq, Wk, Wv, Wo, Wg, WqT, WkT, WvT, WoT, WgT);
    k_embed<<<1024, 256, 0, stream>>>(F_c, t, cb);
    k_proj_qkv<<<dim3(128, 8, 3), 256, 0, stream>>>(cb, WqT, WkT, WvT, bq, bk, bv,
                                                    qb, kbuf, vtb, qscale);
    k_attn2<<<1024, 256, 0, stream>>>(qb, kbuf, vtb, ctxb);
    k_proj_o<<<256, 256, 0, stream>>>(ctxb, WoT, bo, hb);
    k_proj<<<dim3(128, 1), 256, 0, stream>>>(hb, WgT, nullptr, hgT, 1.f, 1, 1);
    k_at_gemm<<<dim3(16, 1, 16), 256, 0, stream>>>(A_t, hgT, feat);
    k_norm<<<16384, 64, 0, stream>>>(feat, nb);
    k_corr<<<dim3(8, 8, 16), 256, 0, stream>>>(nb, out);
}

// Round 6
// 348.528 us; speedup vs baseline: 1.1609x; 1.1609x over previous
//
#include <hip/hip_runtime.h>
#include <math.h>

#define NN 1024
#define DD 128
#define HH 8

typedef __attribute__((ext_vector_type(8))) short short8;
typedef __attribute__((ext_vector_type(4))) float f32x4;

__device__ inline unsigned short f2bf(float x) {
    union { float f; unsigned u; } v; v.f = x;
    return (unsigned short)((v.u + 0x7FFF + ((v.u >> 16) & 1)) >> 16);
}
__device__ inline unsigned pack2(float a, float b) {
    return (unsigned)f2bf(a) | ((unsigned)f2bf(b) << 16);
}

// ---------------- weight prep: transpose fp32 [R][C] -> bf16 [C][R] ----------
__global__ __launch_bounds__(256) void k_prep_w(
    const float* __restrict__ Wq, const float* __restrict__ Wk, const float* __restrict__ Wv,
    const float* __restrict__ Wo, const float* __restrict__ Wg,
    unsigned short* WqT, unsigned short* WkT, unsigned short* WvT,
    unsigned short* WoT, unsigned short* WgT) {
    int id = blockIdx.x;
    const float* src; unsigned short* dst; int R, C, ti;
    if (id < 128)      { src = Wq; dst = WqT; R = 128;  C = 1024; ti = id; }
    else if (id < 256) { src = Wk; dst = WkT; R = 128;  C = 1024; ti = id - 128; }
    else if (id < 384) { src = Wv; dst = WvT; R = 128;  C = 1024; ti = id - 256; }
    else if (id < 512) { src = Wo; dst = WoT; R = 1024; C = 128;  ti = id - 384; }
    else               { src = Wg; dst = WgT; R = 128;  C = 128;  ti = id - 512; }
    int tc = C >> 5;
    int r0 = (ti / tc) << 5, c0 = (ti % tc) << 5;
    __shared__ float T[32][33];
    int tid = threadIdx.x;
    int r = tid >> 3, c4 = (tid & 7) << 2;
    float4 v = *(const float4*)&src[(size_t)(r0 + r) * C + c0 + c4];
    T[r][c4] = v.x; T[r][c4 + 1] = v.y; T[r][c4 + 2] = v.z; T[r][c4 + 3] = v.w;
    __syncthreads();
    int c = tid >> 3, r4 = (tid & 7) << 2;
    uint2 o;
    o.x = pack2(T[r4][c], T[r4 + 1][c]);
    o.y = pack2(T[r4 + 2][c], T[r4 + 3][c]);
    *(uint2*)&dst[(size_t)(c0 + c) * R + r0 + r4] = o;
}

// ---------------- K1: c = bf16(F_c + emb) ------------------------------------
__global__ __launch_bounds__(256) void k_embed(const float* __restrict__ F_c,
                                               const int* __restrict__ t,
                                               unsigned short* __restrict__ cb) {
    int gi = blockIdx.x * 256 + threadIdx.x;    // 262144 chunks of 8
    int row = gi >> 4, ch = gi & 15;
    int b = row >> 10, n = row & 1023;
    float tv = (float)t[b];
    int j = n & 511;
    float e = tv * expf(-(float)j * 0.013518112092919054f);
    float emb = (n < 512) ? sinf(e) : cosf(e);
    const float* src = F_c + (size_t)row * 128 + ch * 8;
    float4 a = *(const float4*)src;
    float4 c4 = *(const float4*)(src + 4);
    uint4 o;
    o.x = pack2(a.x + emb, a.y + emb);  o.y = pack2(a.z + emb, a.w + emb);
    o.z = pack2(c4.x + emb, c4.y + emb); o.w = pack2(c4.z + emb, c4.w + emb);
    *(uint4*)&cb[(size_t)row * 128 + ch * 8] = o;
}

// ---------------- shared GEMM body for the projection kernels ----------------
__device__ __forceinline__ void proj_body(const unsigned short* __restrict__ Ain,
                                          const unsigned short* __restrict__ WT,
                                          const float* __restrict__ bias,
                                          unsigned short* __restrict__ Out,
                                          float scale, int mode, int bh_mul,
                                          unsigned short* sm, int head, int m0) {
    unsigned short* CT  = sm;               // [128][136]
    unsigned short* WTs = sm + 128 * 136;   // [128][136]
    int tid = threadIdx.x;
    int w = tid >> 6, lane = tid & 63, n16 = lane & 15, quad = lane >> 4;
#pragma unroll
    for (int p = 0; p < 8; ++p) {
        int idx = tid + p * 256;
        int r = idx >> 4, ch = idx & 15;
        *(uint4*)&CT[r * 136 + ch * 8]  = *(const uint4*)&Ain[(size_t)(m0 + r) * 128 + ch * 8];
        *(uint4*)&WTs[r * 136 + ch * 8] = *(const uint4*)&WT[(size_t)(head * 128 + r) * 128 + ch * 8];
    }
    __syncthreads();
    int wr = (w >> 1) * 64, wc = (w & 1) * 64;
    f32x4 acc[4][4];
#pragma unroll
    for (int i = 0; i < 4; i++)
#pragma unroll
        for (int j = 0; j < 4; j++) acc[i][j] = (f32x4){0.f, 0.f, 0.f, 0.f};
#pragma unroll
    for (int kk = 0; kk < 4; ++kk) {
        short8 af[4], bf[4];
#pragma unroll
        for (int rb = 0; rb < 4; ++rb)
            af[rb] = *(const short8*)&CT[(wr + rb * 16 + n16) * 136 + kk * 32 + quad * 8];
#pragma unroll
        for (int cb = 0; cb < 4; ++cb)
            bf[cb] = *(const short8*)&WTs[(wc + cb * 16 + n16) * 136 + kk * 32 + quad * 8];
#pragma unroll
        for (int rb = 0; rb < 4; ++rb)
#pragma unroll
            for (int cb = 0; cb < 4; ++cb)
                acc[rb][cb] = __builtin_amdgcn_mfma_f32_16x16x32_bf16(af[rb], bf[cb], acc[rb][cb], 0, 0, 0);
    }
    __syncthreads();    // all frag reads done; reuse CT as bounce
#pragma unroll
    for (int rb = 0; rb < 4; ++rb)
#pragma unroll
        for (int cb = 0; cb < 4; ++cb) {
            int colb = wc + cb * 16 + n16;
            float bs = bias ? bias[head * 128 + colb] : 0.f;
#pragma unroll
            for (int reg = 0; reg < 4; ++reg) {
                int rowb = wr + rb * 16 + quad * 4 + reg;
                unsigned short val = f2bf((acc[rb][cb][reg] + bs) * scale);
                if (mode == 0) CT[rowb * 136 + colb] = val;
                else           CT[colb * 136 + rowb] = val;
            }
        }
    __syncthreads();
    int b = m0 >> 10, n0 = m0 & 1023;
    size_t base = (size_t)(b * bh_mul + head) * 131072;
    if (mode == 0) {
#pragma unroll
        for (int p = 0; p < 8; ++p) {
            int idx = tid + p * 256;
            int r = idx >> 4, ch = idx & 15;
            *(uint4*)&Out[base + (size_t)(n0 + r) * 128 + ch * 8] = *(const uint4*)&CT[r * 136 + ch * 8];
        }
    } else {
#pragma unroll
        for (int p = 0; p < 8; ++p) {
            int idx = tid + p * 256;
            int r = idx >> 4, ch = idx & 15;    // r = out-col row (d), ch over the 128 n's
            *(uint4*)&Out[base + (size_t)r * 1024 + n0 + ch * 8] = *(const uint4*)&CT[r * 136 + ch * 8];
        }
    }
}

// ---------------- K2: fused Q/K/V projections (blockIdx.z selects) -----------
__global__ __launch_bounds__(256) void k_proj_qkv(const unsigned short* __restrict__ Ain,
                                                  const unsigned short* __restrict__ W0,
                                                  const unsigned short* __restrict__ W1,
                                                  const unsigned short* __restrict__ W2,
                                                  const float* __restrict__ b0,
                                                  const float* __restrict__ b1,
                                                  const float* __restrict__ b2,
                                                  unsigned short* __restrict__ O0,
                                                  unsigned short* __restrict__ O1,
                                                  unsigned short* __restrict__ O2,
                                                  float qscale) {
    __shared__ __align__(16) unsigned short sm[2 * 128 * 136];
    int z = blockIdx.z;
    const unsigned short* WT = (z == 0) ? W0 : (z == 1) ? W1 : W2;
    const float* bias = (z == 0) ? b0 : (z == 1) ? b1 : b2;
    unsigned short* Out = (z == 0) ? O0 : (z == 1) ? O1 : O2;
    float scale = (z == 0) ? qscale : 1.f;
    int mode = (z == 2) ? 1 : 0;
    proj_body(Ain, WT, bias, Out, scale, mode, 8, sm, blockIdx.y, blockIdx.x * 128);
}

// ---------------- generic K=128 MFMA GEMM (kept for hgT) ---------------------
__global__ __launch_bounds__(256) void k_proj(const unsigned short* __restrict__ Ain,
                                              const unsigned short* __restrict__ WT,
                                              const float* __restrict__ bias,
                                              unsigned short* __restrict__ Out,
                                              float scale, int mode, int bh_mul) {
    __shared__ __align__(16) unsigned short sm[2 * 128 * 136];
    proj_body(Ain, WT, bias, Out, scale, mode, bh_mul, sm, blockIdx.y, blockIdx.x * 128);
}

// ---------------- K3 attention: compute one 64-key tile ----------------------
__device__ __forceinline__ void attn_compute(const unsigned short* __restrict__ Ksc,
                                             const unsigned short* __restrict__ Vtc,
                                             const short8 (&qf)[2][4],
                                             float (&mrun)[2], float (&lrun)[2],
                                             f32x4 (&O)[2][8], int n16, int quad) {
    // S^T = K Q^T : rows = keys (quad*4+reg within 16-block kb), cols = q (n16)
    f32x4 S[2][4];
#pragma unroll
    for (int qb2 = 0; qb2 < 2; ++qb2)
#pragma unroll
        for (int kb = 0; kb < 4; ++kb) S[qb2][kb] = (f32x4){0.f, 0.f, 0.f, 0.f};
    __builtin_amdgcn_s_setprio(1);
#pragma unroll
    for (int kb = 0; kb < 4; ++kb)
#pragma unroll
        for (int dc = 0; dc < 4; ++dc) {
            short8 kf = *(const short8*)&Ksc[(kb * 16 + n16) * 136 + dc * 32 + quad * 8];
            S[0][kb] = __builtin_amdgcn_mfma_f32_16x16x32_bf16(kf, qf[0][dc], S[0][kb], 0, 0, 0);
            S[1][kb] = __builtin_amdgcn_mfma_f32_16x16x32_bf16(kf, qf[1][dc], S[1][kb], 0, 0, 0);
        }
    __builtin_amdgcn_s_setprio(0);

    // per-q max: local over 16 regs, then across the 4 quads (2 shuffles)
    float mx[2];
#pragma unroll
    for (int qb2 = 0; qb2 < 2; ++qb2) {
        float m = S[qb2][0][0];
#pragma unroll
        for (int kb = 0; kb < 4; ++kb)
#pragma unroll
            for (int reg = 0; reg < 4; ++reg) m = fmaxf(m, S[qb2][kb][reg]);
        m = fmaxf(m, __shfl_xor(m, 16));
        m = fmaxf(m, __shfl_xor(m, 32));
        mx[qb2] = m;
    }
    // defer-max: skip O-rescale when max grew by <= 1 (P bounded by e)
    int keep = (mx[0] - mrun[0] <= 1.f) && (mx[1] - mrun[1] <= 1.f);
    if (!__all(keep)) {
        float mn0 = fmaxf(mrun[0], mx[0]);
        float mn1 = fmaxf(mrun[1], mx[1]);
        float a0 = __expf(mrun[0] - mn0);
        float a1 = __expf(mrun[1] - mn1);
        mrun[0] = mn0; mrun[1] = mn1;
        lrun[0] *= a0; lrun[1] *= a1;
        float av0[4], av1[4];
#pragma unroll
        for (int reg = 0; reg < 4; ++reg) {
            av0[reg] = __shfl(a0, quad * 4 + reg);
            av1[reg] = __shfl(a1, quad * 4 + reg);
        }
#pragma unroll
        for (int dc = 0; dc < 8; ++dc)
#pragma unroll
            for (int reg = 0; reg < 4; ++reg) {
                O[0][dc][reg] *= av0[reg];
                O[1][dc][reg] *= av1[reg];
            }
    }
    // P = exp(S - m), row-sum (2 shuffles), all lane-local
#pragma unroll
    for (int qb2 = 0; qb2 < 2; ++qb2) {
        float ps = 0.f;
#pragma unroll
        for (int kb = 0; kb < 4; ++kb)
#pragma unroll
            for (int reg = 0; reg < 4; ++reg) {
                float p = __expf(S[qb2][kb][reg] - mrun[qb2]);
                S[qb2][kb][reg] = p;
                ps += p;
            }
        ps += __shfl_xor(ps, 16);
        ps += __shfl_xor(ps, 32);
        lrun[qb2] += ps;
    }
    // pack P to bf16 pairs in-register (A-operand dwords)
    unsigned pk01[2][4], pk23[2][4];
#pragma unroll
    for (int qb2 = 0; qb2 < 2; ++qb2)
#pragma unroll
        for (int kb = 0; kb < 4; ++kb) {
            asm("v_cvt_pk_bf16_f32 %0, %1, %2"
                : "=v"(pk01[qb2][kb]) : "v"(S[qb2][kb][0]), "v"(S[qb2][kb][1]));
            asm("v_cvt_pk_bf16_f32 %0, %1, %2"
                : "=v"(pk23[qb2][kb]) : "v"(S[qb2][kb][2]), "v"(S[qb2][kb][3]));
        }
    // O += P V  (B-operand read from permuted Vt matches P's k-slot order)
    __builtin_amdgcn_s_setprio(1);
#pragma unroll
    for (int c = 0; c < 2; ++c) {
        union { uint4 u; short8 s; } pa0, pa1;
        pa0.u = make_uint4(pk01[0][2 * c], pk23[0][2 * c], pk01[0][2 * c + 1], pk23[0][2 * c + 1]);
        pa1.u = make_uint4(pk01[1][2 * c], pk23[1][2 * c], pk01[1][2 * c + 1], pk23[1][2 * c + 1]);
#pragma unroll
        for (int dc = 0; dc < 8; ++dc) {
            short8 vf = *(const short8*)&Vtc[(dc * 16 + n16) * 72 + c * 32 + quad * 8];
            O[0][dc] = __builtin_amdgcn_mfma_f32_16x16x32_bf16(pa0.s, vf, O[0][dc], 0, 0, 0);
            O[1][dc] = __builtin_amdgcn_mfma_f32_16x16x32_bf16(pa1.s, vf, O[1][dc], 0, 0, 0);
        }
    }
    __builtin_amdgcn_s_setprio(0);
}

// ---------------- K3: MFMA flash attention, dbuf LDS, 1 barrier/tile ---------
// Single staging reg set: per tile kt -> {issue loads kt+1} {compute kt from
// buf[kt&1], loads fly under it} {ds_write regs -> buf[(kt+1)&1], vmcnt nearly
// drained} {barrier}. Reg footprint = round-4's no-spill config (104 VGPR).
__global__ __launch_bounds__(256, 2) void k_attn2(const unsigned short* __restrict__ qbuf,
                                                  const unsigned short* __restrict__ kbuf,
                                                  const unsigned short* __restrict__ vtb,
                                                  unsigned short* __restrict__ ctxb) {
    __shared__ __align__(16) unsigned short sm[35840];   // 2 x (Ks[64][136] + Vt[128][72]) = 71680 B
    const int tid = threadIdx.x;
    const int w = tid >> 6, lane = tid & 63;
    const int n16 = lane & 15, quad = lane >> 4;
    const int g = blockIdx.x;
    const int bh = g & 127, tileq = g >> 7;   // bh-major: a (b,h)'s 8 q-tiles share an XCD

    const unsigned short* Qp = qbuf + (size_t)bh * 131072 + (size_t)tileq * 16384;
    const unsigned short* Kp = kbuf + (size_t)bh * 131072;
    const unsigned short* Vp = vtb + (size_t)bh * 131072;

    // Q fragments (B-operand layout: row=n16=q, k=quad*8+j)
    short8 qf[2][4];
#pragma unroll
    for (int qb2 = 0; qb2 < 2; ++qb2)
#pragma unroll
        for (int dc = 0; dc < 4; ++dc)
            qf[qb2][dc] = *(const short8*)&Qp[(size_t)(w * 32 + qb2 * 16 + n16) * 128 + dc * 32 + quad * 8];

    float mrun[2] = {-1e30f, -1e30f};
    float lrun[2] = {0.f, 0.f};
    f32x4 O[2][8];
#pragma unroll
    for (int qb2 = 0; qb2 < 2; ++qb2)
#pragma unroll
        for (int dc = 0; dc < 8; ++dc) O[qb2][dc] = (f32x4){0.f, 0.f, 0.f, 0.f};

    // staging geometry
    const int vr0 = tid >> 3;                          // V: row, +32 per p
    const int k0 = (tid & 7) * 8;
    const int slotA = ((k0 >> 5) << 5) | (((k0 >> 2) & 3) << 3) | (((k0 >> 4) & 1) << 2);

    // single staging register set
    uint4 ka[4], va[4];
#pragma unroll
    for (int p = 0; p < 4; ++p) {
        int idx = tid + p * 256;
        int r = idx >> 4, ch = idx & 15;
        ka[p] = *(const uint4*)&Kp[(size_t)r * 128 + ch * 8];
        va[p] = *(const uint4*)&Vp[(size_t)(vr0 + p * 32) * 1024 + k0];
    }
    // stage tile 0 into buf0
    {
        unsigned short* Kw = sm;
        unsigned short* Vw = sm + 8704;
#pragma unroll
        for (int p = 0; p < 4; ++p) {
            int idx = tid + p * 256;
            int r = idx >> 4, ch = idx & 15;
            *(uint4*)&Kw[r * 136 + ch * 8] = ka[p];
        }
#pragma unroll
        for (int p = 0; p < 4; ++p) {
            int r = vr0 + p * 32;
            *(uint2*)&Vw[r * 72 + slotA]     = make_uint2(va[p].x, va[p].y);
            *(uint2*)&Vw[r * 72 + slotA + 8] = make_uint2(va[p].z, va[p].w);
        }
    }
    __syncthreads();

    for (int kt = 0; kt < 16; ++kt) {
        // 1. issue loads for tile kt+1; they fly under this tile's compute
        if (kt < 15) {
#pragma unroll
            for (int p = 0; p < 4; ++p) {
                int idx = tid + p * 256;
                int r = idx >> 4, ch = idx & 15;
                ka[p] = *(const uint4*)&Kp[(size_t)((kt + 1) * 64 + r) * 128 + ch * 8];
                va[p] = *(const uint4*)&Vp[(size_t)(vr0 + p * 32) * 1024 + (kt + 1) * 64 + k0];
            }
        }
        // 2. compute current tile
        {
            const unsigned short* Ksc = sm + (kt & 1) * 17920;
            const unsigned short* Vtc = Ksc + 8704;
            attn_compute(Ksc, Vtc, qf, mrun, lrun, O, n16, quad);
        }
        // 3. stage tile kt+1 into the other buffer (vmcnt mostly drained)
        if (kt < 15) {
            unsigned short* Kw = sm + ((kt + 1) & 1) * 17920;
            unsigned short* Vw = Kw + 8704;
#pragma unroll
            for (int p = 0; p < 4; ++p) {
                int idx = tid + p * 256;
                int r = idx >> 4, ch = idx & 15;
                *(uint4*)&Kw[r * 136 + ch * 8] = ka[p];
            }
#pragma unroll
            for (int p = 0; p < 4; ++p) {
                int r = vr0 + p * 32;
                *(uint2*)&Vw[r * 72 + slotA]     = make_uint2(va[p].x, va[p].y);
                *(uint2*)&Vw[r * 72 + slotA + 8] = make_uint2(va[p].z, va[p].w);
            }
        }
        // 4. single barrier: next buf visible; current buf reads done
        __syncthreads();
    }

    // epilogue: 1/l lives at q=n16, O rows at q=quad*4+reg -> redistribute once
    float lv[2][4];
#pragma unroll
    for (int qb2 = 0; qb2 < 2; ++qb2)
#pragma unroll
        for (int reg = 0; reg < 4; ++reg)
            lv[qb2][reg] = 1.f / __shfl(lrun[qb2], quad * 4 + reg);
    unsigned short* Ct = sm;    // bounce [128][136] rows of this block's 128 q
#pragma unroll
    for (int qb2 = 0; qb2 < 2; ++qb2)
#pragma unroll
        for (int reg = 0; reg < 4; ++reg) {
            int row = w * 32 + qb2 * 16 + quad * 4 + reg;
#pragma unroll
            for (int dc = 0; dc < 8; ++dc)
                Ct[row * 136 + dc * 16 + n16] = f2bf(O[qb2][dc][reg] * lv[qb2][reg]);
        }
    __syncthreads();
    unsigned short* Outp = ctxb + (size_t)bh * 131072 + (size_t)tileq * 16384;
#pragma unroll
    for (int p = 0; p < 8; ++p) {
        int idx = tid + p * 256;
        int r = idx >> 4, ch = idx & 15;
        *(uint4*)&Outp[(size_t)r * 128 + ch * 8] = *(const uint4*)&Ct[r * 136 + ch * 8];
    }
}

// ---------------- K4: h = ctx @ Wo + bo (M=16384, K=1024, N=128) -------------
__global__ __launch_bounds__(256) void k_proj_o(const unsigned short* __restrict__ Ctxb,
                                                const unsigned short* __restrict__ WoT,
                                                const float* __restrict__ bo,
                                                unsigned short* __restrict__ Hb) {
    __shared__ __align__(16) unsigned short sm[64 * 72 + 128 * 72];
    unsigned short* As = sm;            // [64][72]
    unsigned short* Bs = sm + 64 * 72;  // [128][72]
    int tid = threadIdx.x;
    int m0 = blockIdx.x * 64;
    int b = m0 >> 10, n0 = m0 & 1023;
    int w = tid >> 6, lane = tid & 63, n16 = lane & 15, quad = lane >> 4;
    int wr = (w & 1) * 32, wc = (w >> 1) * 64;
    f32x4 acc[2][4];
#pragma unroll
    for (int i = 0; i < 2; i++)
#pragma unroll
        for (int j = 0; j < 4; j++) acc[i][j] = (f32x4){0.f, 0.f, 0.f, 0.f};
    for (int kt = 0; kt < 16; ++kt) {
        __syncthreads();
        int hh = kt >> 1, d0 = (kt & 1) * 64;
#pragma unroll
        for (int p = 0; p < 2; ++p) {
            int idx = tid + p * 256;
            int r = idx >> 3, ch = idx & 7;
            *(uint4*)&As[r * 72 + ch * 8] =
                *(const uint4*)&Ctxb[((size_t)(b * 8 + hh) * 1024 + n0 + r) * 128 + d0 + ch * 8];
        }
#pragma unroll
        for (int p = 0; p < 4; ++p) {
            int idx = tid + p * 256;
            int r = idx >> 3, ch = idx & 7;
            *(uint4*)&Bs[r * 72 + ch * 8] = *(const uint4*)&WoT[(size_t)r * 1024 + kt * 64 + ch * 8];
        }
        __syncthreads();
#pragma unroll
        for (int kk = 0; kk < 2; ++kk) {
            short8 af0 = *(const short8*)&As[(wr + n16) * 72 + kk * 32 + quad * 8];
            short8 af1 = *(const short8*)&As[(wr + 16 + n16) * 72 + kk * 32 + quad * 8];
#pragma unroll
            for (int cb = 0; cb < 4; ++cb) {
                short8 bf = *(const short8*)&Bs[(wc + cb * 16 + n16) * 72 + kk * 32 + quad * 8];
                acc[0][cb] = __builtin_amdgcn_mfma_f32_16x16x32_bf16(af0, bf, acc[0][cb], 0, 0, 0);
                acc[1][cb] = __builtin_amdgcn_mfma_f32_16x16x32_bf16(af1, bf, acc[1][cb], 0, 0, 0);
            }
        }
    }
    __syncthreads();
    unsigned short* Ct = sm;    // bounce [64][136] (8704 <= 13824)
#pragma unroll
    for (int rb = 0; rb < 2; ++rb)
#pragma unroll
        for (int cb = 0; cb < 4; ++cb) {
            int col = wc + cb * 16 + n16;
            float bs = bo[col];
#pragma unroll
            for (int reg = 0; reg < 4; ++reg)
                Ct[(wr + rb * 16 + quad * 4 + reg) * 136 + col] = f2bf(acc[rb][cb][reg] + bs);
        }
    __syncthreads();
#pragma unroll
    for (int p = 0; p < 4; ++p) {
        int idx = tid + p * 256;
        int r = idx >> 4, ch = idx & 15;
        *(uint4*)&Hb[(size_t)(m0 + r) * 128 + ch * 8] = *(const uint4*)&Ct[r * 136 + ch * 8];
    }
}

// ---------------- K6: feat = relu(A_t @ hg), A_t fp32 cast inline ------------
__global__ __launch_bounds__(256) void k_at_gemm(const float* __restrict__ At,
                                                 const unsigned short* __restrict__ HgT,
                                                 float* __restrict__ Feat) {
    __shared__ __align__(16) unsigned short sm[64 * 72 + 128 * 72];
    unsigned short* As = sm;
    unsigned short* Bs = sm + 64 * 72;
    int tid = threadIdx.x;
    int bz = blockIdx.z;
    int m0 = blockIdx.x * 64;
    int w = tid >> 6, lane = tid & 63, n16 = lane & 15, quad = lane >> 4;
    int wr = (w & 1) * 32, wc = (w >> 1) * 64;
    f32x4 acc[2][4];
#pragma unroll
    for (int i = 0; i < 2; i++)
#pragma unroll
        for (int j = 0; j < 4; j++) acc[i][j] = (f32x4){0.f, 0.f, 0.f, 0.f};
    for (int kt = 0; kt < 16; ++kt) {
        __syncthreads();
#pragma unroll
        for (int p = 0; p < 2; ++p) {
            int idx = tid + p * 256;
            int r = idx >> 3, ch = idx & 7;
            const float* s = At + (size_t)bz * 1048576 + (size_t)(m0 + r) * 1024 + kt * 64 + ch * 8;
            float4 x = *(const float4*)s;
            float4 y = *(const float4*)(s + 4);
            uint4 o;
            o.x = pack2(x.x, x.y); o.y = pack2(x.z, x.w);
            o.z = pack2(y.x, y.y); o.w = pack2(y.z, y.w);
            *(uint4*)&As[r * 72 + ch * 8] = o;
        }
#pragma unroll
        for (int p = 0; p < 4; ++p) {
            int idx = tid + p * 256;
            int r = idx >> 3, ch = idx & 7;
            *(uint4*)&Bs[r * 72 + ch * 8] =
                *(const uint4*)&HgT[(size_t)bz * 131072 + (size_t)r * 1024 + kt * 64 + ch * 8];
        }
        __syncthreads();
#pragma unroll
        for (int kk = 0; kk < 2; ++kk) {
            short8 af0 = *(const short8*)&As[(wr + n16) * 72 + kk * 32 + quad * 8];
            short8 af1 = *(const short8*)&As[(wr + 16 + n16) * 72 + kk * 32 + quad * 8];
#pragma unroll
            for (int cb = 0; cb < 4; ++cb) {
                short8 bf = *(const short8*)&Bs[(wc + cb * 16 + n16) * 72 + kk * 32 + quad * 8];
                acc[0][cb] = __builtin_amdgcn_mfma_f32_16x16x32_bf16(af0, bf, acc[0][cb], 0, 0, 0);
                acc[1][cb] = __builtin_amdgcn_mfma_f32_16x16x32_bf16(af1, bf, acc[1][cb], 0, 0, 0);
            }
        }
    }
#pragma unroll
    for (int rb = 0; rb < 2; ++rb)
#pragma unroll
        for (int cb = 0; cb < 4; ++cb) {
            int col = wc + cb * 16 + n16;
#pragma unroll
            for (int reg = 0; reg < 4; ++reg) {
                int row = m0 + wr + rb * 16 + quad * 4 + reg;
                Feat[(size_t)bz * 131072 + (size_t)row * 128 + col] = fmaxf(acc[rb][cb][reg], 0.f);
            }
        }
}

// ---------------- K7: row normalize fp32 -> bf16 ------------------------------
__global__ __launch_bounds__(64) void k_norm(const float* __restrict__ F,
                                             unsigned short* __restrict__ Nb) {
    int row = blockIdx.x, tdx = threadIdx.x;
    const float* p = F + (size_t)row * 128;
    float2 xy = *(const float2*)&p[tdx * 2];
    float sum = xy.x + xy.y;
#pragma unroll
    for (int off = 32; off; off >>= 1) sum += __shfl_xor(sum, off);
    float mu = sum * (1.f / 128.f);
    float d0 = xy.x - mu, d1 = xy.y - mu;
    float sq = d0 * d0 + d1 * d1;
#pragma unroll
    for (int off = 32; off; off >>= 1) sq += __shfl_xor(sq, off);
    float sd = sqrtf(sq * (1.f / 127.f));
    float inv = 1.f / (sd + 1e-8f);
    ((unsigned*)Nb)[(size_t)row * 64 + tdx] = pack2(d0 * inv, d1 * inv);
}

// ---------------- K8: out[b] = norm @ norm^T / 128 (bf16 MFMA) ----------------
__global__ __launch_bounds__(256) void k_corr(const unsigned short* __restrict__ Nb,
                                              float* __restrict__ Out) {
    __shared__ __align__(16) unsigned short sm[2 * 128 * 136];
    unsigned short* Ar = sm;
    unsigned short* Br = sm + 128 * 136;
    int tid = threadIdx.x;
    int bz = blockIdx.z;
    int n0 = blockIdx.x * 128, m0 = blockIdx.y * 128;
    const unsigned short* base = Nb + (size_t)bz * 131072;
    int w = tid >> 6, lane = tid & 63, n16 = lane & 15, quad = lane >> 4;
#pragma unroll
    for (int p = 0; p < 8; ++p) {
        int idx = tid + p * 256;
        int r = idx >> 4, ch = idx & 15;
        *(uint4*)&Ar[r * 136 + ch * 8] = *(const uint4*)&base[(size_t)(n0 + r) * 128 + ch * 8];
        *(uint4*)&Br[r * 136 + ch * 8] = *(const uint4*)&base[(size_t)(m0 + r) * 128 + ch * 8];
    }
    __syncthreads();
    int wr = (w >> 1) * 64, wc = (w & 1) * 64;
    f32x4 acc[4][4];
#pragma unroll
    for (int i = 0; i < 4; i++)
#pragma unroll
        for (int j = 0; j < 4; j++) acc[i][j] = (f32x4){0.f, 0.f, 0.f, 0.f};
#pragma unroll
    for (int kk = 0; kk < 4; ++kk) {
        short8 af[4], bf[4];
#pragma unroll
        for (int rb = 0; rb < 4; ++rb)
            af[rb] = *(const short8*)&Ar[(wr + rb * 16 + n16) * 136 + kk * 32 + quad * 8];
#pragma unroll
        for (int cb = 0; cb < 4; ++cb)
            bf[cb] = *(const short8*)&Br[(wc + cb * 16 + n16) * 136 + kk * 32 + quad * 8];
#pragma unroll
        for (int rb = 0; rb < 4; ++rb)
#pragma unroll
            for (int cb = 0; cb < 4; ++cb)
                acc[rb][cb] = __builtin_amdgcn_mfma_f32_16x16x32_bf16(af[rb], bf[cb], acc[rb][cb], 0, 0, 0);
    }
#pragma unroll
    for (int rb = 0; rb < 4; ++rb)
#pragma unroll
        for (int cb = 0; cb < 4; ++cb)
#pragma unroll
            for (int reg = 0; reg < 4; ++reg) {
                int row = n0 + wr + rb * 16 + quad * 4 + reg;
                int col = m0 + wc + cb * 16 + n16;
                Out[(size_t)bz * 1048576 + (size_t)row * 1024 + col] = acc[rb][cb][reg] * 0.0078125f;
            }
}

extern "C" void kernel_launch(void* const* d_in, const int* in_sizes, int n_in,
                              void* d_out, int out_size, void* d_ws, size_t ws_size,
                              hipStream_t stream) {
    const float* A_t = (const float*)d_in[0];
    const float* F_c = (const float*)d_in[1];
    const int*   t   = (const int*)d_in[2];
    const float* Wq  = (const float*)d_in[3];
    const float* bq  = (const float*)d_in[4];
    const float* Wk  = (const float*)d_in[5];
    const float* bk  = (const float*)d_in[6];
    const float* Wv  = (const float*)d_in[7];
    const float* bv  = (const float*)d_in[8];
    const float* Wo  = (const float*)d_in[9];
    const float* bo  = (const float*)d_in[10];
    const float* Wg  = (const float*)d_in[11];
    float* out = (float*)d_out;
    char* ws = (char*)d_ws;

    unsigned short* cb   = (unsigned short*)(ws);                 //  4 MB
    unsigned short* qb   = (unsigned short*)(ws + 4194304);       // 33.5 MB
    unsigned short* kbuf = (unsigned short*)(ws + 37748736);
    unsigned short* vtb  = (unsigned short*)(ws + 71303168);
    unsigned short* ctxb = (unsigned short*)(ws + 104857600);
    unsigned short* hb   = (unsigned short*)(ws + 138412032);     //  4 MB
    unsigned short* hgT  = (unsigned short*)(ws + 142606336);     //  4 MB
    float*          feat = (float*)        (ws + 146800640);      //  8 MB
    unsigned short* nb   = (unsigned short*)(ws + 155189248);     //  4 MB
    unsigned short* WqT  = (unsigned short*)(ws + 159383552);
    unsigned short* WkT  = (unsigned short*)(ws + 159645696);
    unsigned short* WvT  = (unsigned short*)(ws + 159907840);
    unsigned short* WoT  = (unsigned short*)(ws + 160169984);
    unsigned short* WgT  = (unsigned short*)(ws + 160432128);

    const float qscale = 0.08838834764831845f;   // 1/sqrt(128)

    k_prep_w<<<528, 256, 0, stream>>>(Wq, Wk, Wv, Wo, Wg, WqT, WkT, WvT, WoT, WgT);
    k_embed<<<1024, 256, 0, stream>>>(F_c, t, cb);
    k_proj_qkv<<<dim3(128, 8, 3), 256, 0, stream>>>(cb, WqT, WkT, WvT, bq, bk, bv,
                                                    qb, kbuf, vtb, qscale);
    k_attn2<<<1024, 256, 0, stream>>>(qb, kbuf, vtb, ctxb);
    k_proj_o<<<256, 256, 0, stream>>>(ctxb, WoT, bo, hb);
    k_proj<<<dim3(128, 1), 256, 0, stream>>>(hb, WgT, nullptr, hgT, 1.f, 1, 1);
    k_at_gemm<<<dim3(16, 1, 16), 256, 0, stream>>>(A_t, hgT, feat);
    k_norm<<<16384, 64, 0, stream>>>(feat, nb);
    k_corr<<<dim3(8, 8, 16), 256, 0, stream>>>(nb, out);
}

// Round 7
// 321.619 us; speedup vs baseline: 1.2581x; 1.0837x over previous
//
#include <hip/hip_runtime.h>
#include <math.h>

#define NN 1024
#define DD 128
#define HH 8

typedef __attribute__((ext_vector_type(8))) short short8;
typedef __attribute__((ext_vector_type(4))) float f32x4;

__device__ inline unsigned short f2bf(float x) {
    union { float f; unsigned u; } v; v.f = x;
    return (unsigned short)((v.u + 0x7FFF + ((v.u >> 16) & 1)) >> 16);
}
__device__ inline unsigned pack2(float a, float b) {
    return (unsigned)f2bf(a) | ((unsigned)f2bf(b) << 16);
}

// ---------------- weight prep: transpose fp32 [R][C] -> bf16 [C][R] ----------
__global__ __launch_bounds__(256) void k_prep_w(
    const float* __restrict__ Wq, const float* __restrict__ Wk, const float* __restrict__ Wv,
    const float* __restrict__ Wo, const float* __restrict__ Wg,
    unsigned short* WqT, unsigned short* WkT, unsigned short* WvT,
    unsigned short* WoT, unsigned short* WgT) {
    int id = blockIdx.x;
    const float* src; unsigned short* dst; int R, C, ti;
    if (id < 128)      { src = Wq; dst = WqT; R = 128;  C = 1024; ti = id; }
    else if (id < 256) { src = Wk; dst = WkT; R = 128;  C = 1024; ti = id - 128; }
    else if (id < 384) { src = Wv; dst = WvT; R = 128;  C = 1024; ti = id - 256; }
    else if (id < 512) { src = Wo; dst = WoT; R = 1024; C = 128;  ti = id - 384; }
    else               { src = Wg; dst = WgT; R = 128;  C = 128;  ti = id - 512; }
    int tc = C >> 5;
    int r0 = (ti / tc) << 5, c0 = (ti % tc) << 5;
    __shared__ float T[32][33];
    int tid = threadIdx.x;
    int r = tid >> 3, c4 = (tid & 7) << 2;
    float4 v = *(const float4*)&src[(size_t)(r0 + r) * C + c0 + c4];
    T[r][c4] = v.x; T[r][c4 + 1] = v.y; T[r][c4 + 2] = v.z; T[r][c4 + 3] = v.w;
    __syncthreads();
    int c = tid >> 3, r4 = (tid & 7) << 2;
    uint2 o;
    o.x = pack2(T[r4][c], T[r4 + 1][c]);
    o.y = pack2(T[r4 + 2][c], T[r4 + 3][c]);
    *(uint2*)&dst[(size_t)(c0 + c) * R + r0 + r4] = o;
}

// ---------------- K1: c = bf16(F_c + emb) ------------------------------------
__global__ __launch_bounds__(256) void k_embed(const float* __restrict__ F_c,
                                               const int* __restrict__ t,
                                               unsigned short* __restrict__ cb) {
    int gi = blockIdx.x * 256 + threadIdx.x;    // 262144 chunks of 8
    int row = gi >> 4, ch = gi & 15;
    int b = row >> 10, n = row & 1023;
    float tv = (float)t[b];
    int j = n & 511;
    float e = tv * expf(-(float)j * 0.013518112092919054f);
    float emb = (n < 512) ? sinf(e) : cosf(e);
    const float* src = F_c + (size_t)row * 128 + ch * 8;
    float4 a = *(const float4*)src;
    float4 c4 = *(const float4*)(src + 4);
    uint4 o;
    o.x = pack2(a.x + emb, a.y + emb);  o.y = pack2(a.z + emb, a.w + emb);
    o.z = pack2(c4.x + emb, c4.y + emb); o.w = pack2(c4.z + emb, c4.w + emb);
    *(uint4*)&cb[(size_t)row * 128 + ch * 8] = o;
}

// ---------------- shared GEMM body for the projection kernels ----------------
__device__ __forceinline__ void proj_body(const unsigned short* __restrict__ Ain,
                                          const unsigned short* __restrict__ WT,
                                          const float* __restrict__ bias,
                                          unsigned short* __restrict__ Out,
                                          float scale, int mode, int bh_mul,
                                          unsigned short* sm, int head, int m0) {
    unsigned short* CT  = sm;               // [128][136]
    unsigned short* WTs = sm + 128 * 136;   // [128][136]
    int tid = threadIdx.x;
    int w = tid >> 6, lane = tid & 63, n16 = lane & 15, quad = lane >> 4;
#pragma unroll
    for (int p = 0; p < 8; ++p) {
        int idx = tid + p * 256;
        int r = idx >> 4, ch = idx & 15;
        *(uint4*)&CT[r * 136 + ch * 8]  = *(const uint4*)&Ain[(size_t)(m0 + r) * 128 + ch * 8];
        *(uint4*)&WTs[r * 136 + ch * 8] = *(const uint4*)&WT[(size_t)(head * 128 + r) * 128 + ch * 8];
    }
    __syncthreads();
    int wr = (w >> 1) * 64, wc = (w & 1) * 64;
    f32x4 acc[4][4];
#pragma unroll
    for (int i = 0; i < 4; i++)
#pragma unroll
        for (int j = 0; j < 4; j++) acc[i][j] = (f32x4){0.f, 0.f, 0.f, 0.f};
#pragma unroll
    for (int kk = 0; kk < 4; ++kk) {
        short8 af[4], bf[4];
#pragma unroll
        for (int rb = 0; rb < 4; ++rb)
            af[rb] = *(const short8*)&CT[(wr + rb * 16 + n16) * 136 + kk * 32 + quad * 8];
#pragma unroll
        for (int cb = 0; cb < 4; ++cb)
            bf[cb] = *(const short8*)&WTs[(wc + cb * 16 + n16) * 136 + kk * 32 + quad * 8];
#pragma unroll
        for (int rb = 0; rb < 4; ++rb)
#pragma unroll
            for (int cb = 0; cb < 4; ++cb)
                acc[rb][cb] = __builtin_amdgcn_mfma_f32_16x16x32_bf16(af[rb], bf[cb], acc[rb][cb], 0, 0, 0);
    }
    __syncthreads();    // all frag reads done; reuse CT as bounce
#pragma unroll
    for (int rb = 0; rb < 4; ++rb)
#pragma unroll
        for (int cb = 0; cb < 4; ++cb) {
            int colb = wc + cb * 16 + n16;
            float bs = bias ? bias[head * 128 + colb] : 0.f;
#pragma unroll
            for (int reg = 0; reg < 4; ++reg) {
                int rowb = wr + rb * 16 + quad * 4 + reg;
                unsigned short val = f2bf((acc[rb][cb][reg] + bs) * scale);
                if (mode == 0) CT[rowb * 136 + colb] = val;
                else           CT[colb * 136 + rowb] = val;
            }
        }
    __syncthreads();
    int b = m0 >> 10, n0 = m0 & 1023;
    size_t base = (size_t)(b * bh_mul + head) * 131072;
    if (mode == 0) {
#pragma unroll
        for (int p = 0; p < 8; ++p) {
            int idx = tid + p * 256;
            int r = idx >> 4, ch = idx & 15;
            *(uint4*)&Out[base + (size_t)(n0 + r) * 128 + ch * 8] = *(const uint4*)&CT[r * 136 + ch * 8];
        }
    } else {
#pragma unroll
        for (int p = 0; p < 8; ++p) {
            int idx = tid + p * 256;
            int r = idx >> 4, ch = idx & 15;    // r = out-col row (d), ch over the 128 n's
            *(uint4*)&Out[base + (size_t)r * 1024 + n0 + ch * 8] = *(const uint4*)&CT[r * 136 + ch * 8];
        }
    }
}

// ---------------- K2: fused Q/K/V projections (blockIdx.z selects) -----------
__global__ __launch_bounds__(256) void k_proj_qkv(const unsigned short* __restrict__ Ain,
                                                  const unsigned short* __restrict__ W0,
                                                  const unsigned short* __restrict__ W1,
                                                  const unsigned short* __restrict__ W2,
                                                  const float* __restrict__ b0,
                                                  const float* __restrict__ b1,
                                                  const float* __restrict__ b2,
                                                  unsigned short* __restrict__ O0,
                                                  unsigned short* __restrict__ O1,
                                                  unsigned short* __restrict__ O2,
                                                  float qscale) {
    __shared__ __align__(16) unsigned short sm[2 * 128 * 136];
    int z = blockIdx.z;
    const unsigned short* WT = (z == 0) ? W0 : (z == 1) ? W1 : W2;
    const float* bias = (z == 0) ? b0 : (z == 1) ? b1 : b2;
    unsigned short* Out = (z == 0) ? O0 : (z == 1) ? O1 : O2;
    float scale = (z == 0) ? qscale : 1.f;
    int mode = (z == 2) ? 1 : 0;
    proj_body(Ain, WT, bias, Out, scale, mode, 8, sm, blockIdx.y, blockIdx.x * 128);
}

// ---------------- generic K=128 MFMA GEMM (kept for hgT) ---------------------
__global__ __launch_bounds__(256) void k_proj(const unsigned short* __restrict__ Ain,
                                              const unsigned short* __restrict__ WT,
                                              const float* __restrict__ bias,
                                              unsigned short* __restrict__ Out,
                                              float scale, int mode, int bh_mul) {
    __shared__ __align__(16) unsigned short sm[2 * 128 * 136];
    proj_body(Ain, WT, bias, Out, scale, mode, bh_mul, sm, blockIdx.y, blockIdx.x * 128);
}

// ---------------- K3 attention: compute one 64-key tile ----------------------
// Ks [64][128] and Vt [128][64] are XOR-swizzled: short col ^= (row&7)<<3.
__device__ __forceinline__ void attn_compute(const unsigned short* __restrict__ Ksc,
                                             const unsigned short* __restrict__ Vtc,
                                             const short8 (&qf)[2][4],
                                             float (&mrun)[2], float (&lrun)[2],
                                             f32x4 (&O)[2][8], int n16, int quad) {
    const int swz = (n16 & 7) << 3;
    // S^T = K Q^T : rows = keys (quad*4+reg within 16-block kb), cols = q (n16)
    f32x4 S[2][4];
#pragma unroll
    for (int qb2 = 0; qb2 < 2; ++qb2)
#pragma unroll
        for (int kb = 0; kb < 4; ++kb) S[qb2][kb] = (f32x4){0.f, 0.f, 0.f, 0.f};
    __builtin_amdgcn_s_setprio(1);
#pragma unroll
    for (int kb = 0; kb < 4; ++kb)
#pragma unroll
        for (int dc = 0; dc < 4; ++dc) {
            short8 kf = *(const short8*)&Ksc[((kb * 16 + n16) << 7) + ((dc * 32 + quad * 8) ^ swz)];
            S[0][kb] = __builtin_amdgcn_mfma_f32_16x16x32_bf16(kf, qf[0][dc], S[0][kb], 0, 0, 0);
            S[1][kb] = __builtin_amdgcn_mfma_f32_16x16x32_bf16(kf, qf[1][dc], S[1][kb], 0, 0, 0);
        }
    __builtin_amdgcn_s_setprio(0);

    // per-q max: local over 16 regs, then across the 4 quads (2 shuffles)
    float mx[2];
#pragma unroll
    for (int qb2 = 0; qb2 < 2; ++qb2) {
        float m = S[qb2][0][0];
#pragma unroll
        for (int kb = 0; kb < 4; ++kb)
#pragma unroll
            for (int reg = 0; reg < 4; ++reg) m = fmaxf(m, S[qb2][kb][reg]);
        m = fmaxf(m, __shfl_xor(m, 16));
        m = fmaxf(m, __shfl_xor(m, 32));
        mx[qb2] = m;
    }
    // defer-max: skip O-rescale when max grew by <= 1 (P bounded by e)
    int keep = (mx[0] - mrun[0] <= 1.f) && (mx[1] - mrun[1] <= 1.f);
    if (!__all(keep)) {
        float mn0 = fmaxf(mrun[0], mx[0]);
        float mn1 = fmaxf(mrun[1], mx[1]);
        float a0 = __expf(mrun[0] - mn0);
        float a1 = __expf(mrun[1] - mn1);
        mrun[0] = mn0; mrun[1] = mn1;
        lrun[0] *= a0; lrun[1] *= a1;
        float av0[4], av1[4];
#pragma unroll
        for (int reg = 0; reg < 4; ++reg) {
            av0[reg] = __shfl(a0, quad * 4 + reg);
            av1[reg] = __shfl(a1, quad * 4 + reg);
        }
#pragma unroll
        for (int dc = 0; dc < 8; ++dc)
#pragma unroll
            for (int reg = 0; reg < 4; ++reg) {
                O[0][dc][reg] *= av0[reg];
                O[1][dc][reg] *= av1[reg];
            }
    }
    // P = exp(S - m), row-sum (2 shuffles), all lane-local
#pragma unroll
    for (int qb2 = 0; qb2 < 2; ++qb2) {
        float ps = 0.f;
#pragma unroll
        for (int kb = 0; kb < 4; ++kb)
#pragma unroll
            for (int reg = 0; reg < 4; ++reg) {
                float p = __expf(S[qb2][kb][reg] - mrun[qb2]);
                S[qb2][kb][reg] = p;
                ps += p;
            }
        ps += __shfl_xor(ps, 16);
        ps += __shfl_xor(ps, 32);
        lrun[qb2] += ps;
    }
    // pack P to bf16 pairs in-register (A-operand dwords)
    unsigned pk01[2][4], pk23[2][4];
#pragma unroll
    for (int qb2 = 0; qb2 < 2; ++qb2)
#pragma unroll
        for (int kb = 0; kb < 4; ++kb) {
            asm("v_cvt_pk_bf16_f32 %0, %1, %2"
                : "=v"(pk01[qb2][kb]) : "v"(S[qb2][kb][0]), "v"(S[qb2][kb][1]));
            asm("v_cvt_pk_bf16_f32 %0, %1, %2"
                : "=v"(pk23[qb2][kb]) : "v"(S[qb2][kb][2]), "v"(S[qb2][kb][3]));
        }
    // O += P V  (B-operand read from permuted Vt matches P's k-slot order)
    __builtin_amdgcn_s_setprio(1);
#pragma unroll
    for (int c = 0; c < 2; ++c) {
        union { uint4 u; short8 s; } pa0, pa1;
        pa0.u = make_uint4(pk01[0][2 * c], pk23[0][2 * c], pk01[0][2 * c + 1], pk23[0][2 * c + 1]);
        pa1.u = make_uint4(pk01[1][2 * c], pk23[1][2 * c], pk01[1][2 * c + 1], pk23[1][2 * c + 1]);
#pragma unroll
        for (int dc = 0; dc < 8; ++dc) {
            short8 vf = *(const short8*)&Vtc[((dc * 16 + n16) << 6) + ((c * 32 + quad * 8) ^ swz)];
            O[0][dc] = __builtin_amdgcn_mfma_f32_16x16x32_bf16(pa0.s, vf, O[0][dc], 0, 0, 0);
            O[1][dc] = __builtin_amdgcn_mfma_f32_16x16x32_bf16(pa1.s, vf, O[1][dc], 0, 0, 0);
        }
    }
    __builtin_amdgcn_s_setprio(0);
}

// ---------------- K3: MFMA flash attention, dbuf swizzled LDS ----------------
__global__ __launch_bounds__(256, 2) void k_attn2(const unsigned short* __restrict__ qbuf,
                                                  const unsigned short* __restrict__ kbuf,
                                                  const unsigned short* __restrict__ vtb,
                                                  unsigned short* __restrict__ ctxb) {
    __shared__ __align__(16) unsigned short sm[32768];   // 2 x (Ks 64x128 + Vt 128x64) = 64 KB
    const int tid = threadIdx.x;
    const int w = tid >> 6, lane = tid & 63;
    const int n16 = lane & 15, quad = lane >> 4;
    const int g = blockIdx.x;
    const int bh = g & 127, tileq = g >> 7;   // bh-major: a (b,h)'s 8 q-tiles share an XCD

    const unsigned short* Qp = qbuf + (size_t)bh * 131072 + (size_t)tileq * 16384;
    const unsigned short* Kp = kbuf + (size_t)bh * 131072;
    const unsigned short* Vp = vtb + (size_t)bh * 131072;

    // Q fragments (B-operand layout: row=n16=q, k=quad*8+j)
    short8 qf[2][4];
#pragma unroll
    for (int qb2 = 0; qb2 < 2; ++qb2)
#pragma unroll
        for (int dc = 0; dc < 4; ++dc)
            qf[qb2][dc] = *(const short8*)&Qp[(size_t)(w * 32 + qb2 * 16 + n16) * 128 + dc * 32 + quad * 8];

    float mrun[2] = {-1e30f, -1e30f};
    float lrun[2] = {0.f, 0.f};
    f32x4 O[2][8];
#pragma unroll
    for (int qb2 = 0; qb2 < 2; ++qb2)
#pragma unroll
        for (int dc = 0; dc < 8; ++dc) O[qb2][dc] = (f32x4){0.f, 0.f, 0.f, 0.f};

    // staging geometry (XOR-swizzled LDS addressing)
    const int vr0 = tid >> 3;                          // V: row, +32 per p
    const int k0 = (tid & 7) * 8;
    const int slotA = ((k0 >> 5) << 5) | (((k0 >> 2) & 3) << 3) | (((k0 >> 4) & 1) << 2);
    const int voff = slotA ^ ((vr0 & 7) << 3);         // slotA bit3==0 -> slotA+8 == slotA^8
    const int kr0 = tid >> 4, kch = tid & 15;          // K: row kr0+p*16, 16B chunk kch
    const int kwoff = ((kch ^ (kr0 & 7)) << 3);

    // single staging register set
    uint4 ka[4], va[4];
#pragma unroll
    for (int p = 0; p < 4; ++p) {
        ka[p] = *(const uint4*)&Kp[(size_t)(kr0 + p * 16) * 128 + kch * 8];
        va[p] = *(const uint4*)&Vp[(size_t)(vr0 + p * 32) * 1024 + k0];
    }
    // stage tile 0 into buf0
    {
        unsigned short* Kw = sm;
        unsigned short* Vw = sm + 8192;
#pragma unroll
        for (int p = 0; p < 4; ++p)
            *(uint4*)&Kw[((kr0 + p * 16) << 7) + kwoff] = ka[p];
#pragma unroll
        for (int p = 0; p < 4; ++p) {
            int rb6 = (vr0 + p * 32) << 6;
            *(uint2*)&Vw[rb6 + voff]       = make_uint2(va[p].x, va[p].y);
            *(uint2*)&Vw[rb6 + (voff ^ 8)] = make_uint2(va[p].z, va[p].w);
        }
    }
    __syncthreads();

    for (int kt = 0; kt < 16; ++kt) {
        // 1. issue loads for tile kt+1; they fly under this tile's compute
        if (kt < 15) {
#pragma unroll
            for (int p = 0; p < 4; ++p) {
                ka[p] = *(const uint4*)&Kp[(size_t)((kt + 1) * 64 + kr0 + p * 16) * 128 + kch * 8];
                va[p] = *(const uint4*)&Vp[(size_t)(vr0 + p * 32) * 1024 + (kt + 1) * 64 + k0];
            }
        }
        // 2. compute current tile
        {
            const unsigned short* Ksc = sm + (kt & 1) * 16384;
            const unsigned short* Vtc = Ksc + 8192;
            attn_compute(Ksc, Vtc, qf, mrun, lrun, O, n16, quad);
        }
        // 3. stage tile kt+1 into the other buffer (vmcnt mostly drained)
        if (kt < 15) {
            unsigned short* Kw = sm + ((kt + 1) & 1) * 16384;
            unsigned short* Vw = Kw + 8192;
#pragma unroll
            for (int p = 0; p < 4; ++p)
                *(uint4*)&Kw[((kr0 + p * 16) << 7) + kwoff] = ka[p];
#pragma unroll
            for (int p = 0; p < 4; ++p) {
                int rb6 = (vr0 + p * 32) << 6;
                *(uint2*)&Vw[rb6 + voff]       = make_uint2(va[p].x, va[p].y);
                *(uint2*)&Vw[rb6 + (voff ^ 8)] = make_uint2(va[p].z, va[p].w);
            }
        }
        // 4. single barrier: next buf visible; current buf reads done
        __syncthreads();
    }

    // epilogue: 1/l lives at q=n16, O rows at q=quad*4+reg -> redistribute once
    float lv[2][4];
#pragma unroll
    for (int qb2 = 0; qb2 < 2; ++qb2)
#pragma unroll
        for (int reg = 0; reg < 4; ++reg)
            lv[qb2][reg] = 1.f / __shfl(lrun[qb2], quad * 4 + reg);
    unsigned short* Ct = sm;    // bounce [128][136] rows of this block's 128 q
#pragma unroll
    for (int qb2 = 0; qb2 < 2; ++qb2)
#pragma unroll
        for (int reg = 0; reg < 4; ++reg) {
            int row = w * 32 + qb2 * 16 + quad * 4 + reg;
#pragma unroll
            for (int dc = 0; dc < 8; ++dc)
                Ct[row * 136 + dc * 16 + n16] = f2bf(O[qb2][dc][reg] * lv[qb2][reg]);
        }
    __syncthreads();
    unsigned short* Outp = ctxb + (size_t)bh * 131072 + (size_t)tileq * 16384;
#pragma unroll
    for (int p = 0; p < 8; ++p) {
        int idx = tid + p * 256;
        int r = idx >> 4, ch = idx & 15;
        *(uint4*)&Outp[(size_t)r * 128 + ch * 8] = *(const uint4*)&Ct[r * 136 + ch * 8];
    }
}

// ---------------- K4: h = ctx @ Wo + bo — reg-staged dbuf, 1 barrier/iter ----
__global__ __launch_bounds__(256) void k_proj_o(const unsigned short* __restrict__ Ctxb,
                                                const unsigned short* __restrict__ WoT,
                                                const float* __restrict__ bo,
                                                unsigned short* __restrict__ Hb) {
    __shared__ __align__(16) unsigned short sm[2 * 13824];  // dbuf: As[64][72]+Bs[128][72]
    int tid = threadIdx.x;
    int m0 = blockIdx.x * 64;
    int b = m0 >> 10, n0 = m0 & 1023;
    int w = tid >> 6, lane = tid & 63, n16 = lane & 15, quad = lane >> 4;
    int wr = (w & 1) * 32, wc = (w >> 1) * 64;
    int r8 = tid >> 3, ch8 = tid & 7;
    f32x4 acc[2][4];
#pragma unroll
    for (int i = 0; i < 2; i++)
#pragma unroll
        for (int j = 0; j < 4; j++) acc[i][j] = (f32x4){0.f, 0.f, 0.f, 0.f};
    uint4 aR[2], bR[4];
#pragma unroll
    for (int p = 0; p < 2; ++p)
        aR[p] = *(const uint4*)&Ctxb[((size_t)(b * 8) * 1024 + n0 + r8 + p * 32) * 128 + ch8 * 8];
#pragma unroll
    for (int p = 0; p < 4; ++p)
        bR[p] = *(const uint4*)&WoT[(size_t)(r8 + p * 32) * 1024 + ch8 * 8];
    {
        unsigned short* As = sm;
        unsigned short* Bs = sm + 64 * 72;
#pragma unroll
        for (int p = 0; p < 2; ++p) *(uint4*)&As[(r8 + p * 32) * 72 + ch8 * 8] = aR[p];
#pragma unroll
        for (int p = 0; p < 4; ++p) *(uint4*)&Bs[(r8 + p * 32) * 72 + ch8 * 8] = bR[p];
    }
    __syncthreads();
    for (int kt = 0; kt < 16; ++kt) {
        if (kt < 15) {
            int kn = kt + 1, hh = kn >> 1, d0 = (kn & 1) * 64;
#pragma unroll
            for (int p = 0; p < 2; ++p)
                aR[p] = *(const uint4*)&Ctxb[((size_t)(b * 8 + hh) * 1024 + n0 + r8 + p * 32) * 128 + d0 + ch8 * 8];
#pragma unroll
            for (int p = 0; p < 4; ++p)
                bR[p] = *(const uint4*)&WoT[(size_t)(r8 + p * 32) * 1024 + kn * 64 + ch8 * 8];
        }
        const unsigned short* As = sm + (kt & 1) * 13824;
        const unsigned short* Bs = As + 64 * 72;
#pragma unroll
        for (int kk = 0; kk < 2; ++kk) {
            short8 af0 = *(const short8*)&As[(wr + n16) * 72 + kk * 32 + quad * 8];
            short8 af1 = *(const short8*)&As[(wr + 16 + n16) * 72 + kk * 32 + quad * 8];
#pragma unroll
            for (int cb = 0; cb < 4; ++cb) {
                short8 bf = *(const short8*)&Bs[(wc + cb * 16 + n16) * 72 + kk * 32 + quad * 8];
                acc[0][cb] = __builtin_amdgcn_mfma_f32_16x16x32_bf16(af0, bf, acc[0][cb], 0, 0, 0);
                acc[1][cb] = __builtin_amdgcn_mfma_f32_16x16x32_bf16(af1, bf, acc[1][cb], 0, 0, 0);
            }
        }
        if (kt < 15) {
            unsigned short* Aw = sm + ((kt + 1) & 1) * 13824;
            unsigned short* Bw = Aw + 64 * 72;
#pragma unroll
            for (int p = 0; p < 2; ++p) *(uint4*)&Aw[(r8 + p * 32) * 72 + ch8 * 8] = aR[p];
#pragma unroll
            for (int p = 0; p < 4; ++p) *(uint4*)&Bw[(r8 + p * 32) * 72 + ch8 * 8] = bR[p];
        }
        __syncthreads();
    }
    unsigned short* Ct = sm;    // bounce [64][136] (8704 <= 13824)
#pragma unroll
    for (int rb = 0; rb < 2; ++rb)
#pragma unroll
        for (int cb = 0; cb < 4; ++cb) {
            int col = wc + cb * 16 + n16;
            float bs = bo[col];
#pragma unroll
            for (int reg = 0; reg < 4; ++reg)
                Ct[(wr + rb * 16 + quad * 4 + reg) * 136 + col] = f2bf(acc[rb][cb][reg] + bs);
        }
    __syncthreads();
#pragma unroll
    for (int p = 0; p < 4; ++p) {
        int idx = tid + p * 256;
        int r = idx >> 4, ch = idx & 15;
        *(uint4*)&Hb[(size_t)(m0 + r) * 128 + ch * 8] = *(const uint4*)&Ct[r * 136 + ch * 8];
    }
}

// ---------------- K6: feat = relu(A_t @ hg) — reg-staged dbuf pipeline -------
__global__ __launch_bounds__(256) void k_at_gemm(const float* __restrict__ At,
                                                 const unsigned short* __restrict__ HgT,
                                                 float* __restrict__ Feat) {
    __shared__ __align__(16) unsigned short sm[2 * 13824];
    int tid = threadIdx.x;
    int bz = blockIdx.z;
    int m0 = blockIdx.x * 64;
    int w = tid >> 6, lane = tid & 63, n16 = lane & 15, quad = lane >> 4;
    int wr = (w & 1) * 32, wc = (w >> 1) * 64;
    int r8 = tid >> 3, ch8 = tid & 7;
    f32x4 acc[2][4];
#pragma unroll
    for (int i = 0; i < 2; i++)
#pragma unroll
        for (int j = 0; j < 4; j++) acc[i][j] = (f32x4){0.f, 0.f, 0.f, 0.f};
    float4 axR[2], ayR[2]; uint4 bR[4];
#pragma unroll
    for (int p = 0; p < 2; ++p) {
        const float* s = At + (size_t)bz * 1048576 + (size_t)(m0 + r8 + p * 32) * 1024 + ch8 * 8;
        axR[p] = *(const float4*)s;
        ayR[p] = *(const float4*)(s + 4);
    }
#pragma unroll
    for (int p = 0; p < 4; ++p)
        bR[p] = *(const uint4*)&HgT[(size_t)bz * 131072 + (size_t)(r8 + p * 32) * 1024 + ch8 * 8];
    {
        unsigned short* As = sm;
        unsigned short* Bs = sm + 64 * 72;
#pragma unroll
        for (int p = 0; p < 2; ++p) {
            uint4 o;
            o.x = pack2(axR[p].x, axR[p].y); o.y = pack2(axR[p].z, axR[p].w);
            o.z = pack2(ayR[p].x, ayR[p].y); o.w = pack2(ayR[p].z, ayR[p].w);
            *(uint4*)&As[(r8 + p * 32) * 72 + ch8 * 8] = o;
        }
#pragma unroll
        for (int p = 0; p < 4; ++p) *(uint4*)&Bs[(r8 + p * 32) * 72 + ch8 * 8] = bR[p];
    }
    __syncthreads();
    for (int kt = 0; kt < 16; ++kt) {
        if (kt < 15) {
            int kn = kt + 1;
#pragma unroll
            for (int p = 0; p < 2; ++p) {
                const float* s = At + (size_t)bz * 1048576 + (size_t)(m0 + r8 + p * 32) * 1024 + kn * 64 + ch8 * 8;
                axR[p] = *(const float4*)s;
                ayR[p] = *(const float4*)(s + 4);
            }
#pragma unroll
            for (int p = 0; p < 4; ++p)
                bR[p] = *(const uint4*)&HgT[(size_t)bz * 131072 + (size_t)(r8 + p * 32) * 1024 + kn * 64 + ch8 * 8];
        }
        const unsigned short* As = sm + (kt & 1) * 13824;
        const unsigned short* Bs = As + 64 * 72;
#pragma unroll
        for (int kk = 0; kk < 2; ++kk) {
            short8 af0 = *(const short8*)&As[(wr + n16) * 72 + kk * 32 + quad * 8];
            short8 af1 = *(const short8*)&As[(wr + 16 + n16) * 72 + kk * 32 + quad * 8];
#pragma unroll
            for (int cb = 0; cb < 4; ++cb) {
                short8 bf = *(const short8*)&Bs[(wc + cb * 16 + n16) * 72 + kk * 32 + quad * 8];
                acc[0][cb] = __builtin_amdgcn_mfma_f32_16x16x32_bf16(af0, bf, acc[0][cb], 0, 0, 0);
                acc[1][cb] = __builtin_amdgcn_mfma_f32_16x16x32_bf16(af1, bf, acc[1][cb], 0, 0, 0);
            }
        }
        if (kt < 15) {
            unsigned short* Aw = sm + ((kt + 1) & 1) * 13824;
            unsigned short* Bw = Aw + 64 * 72;
#pragma unroll
            for (int p = 0; p < 2; ++p) {
                uint4 o;
                o.x = pack2(axR[p].x, axR[p].y); o.y = pack2(axR[p].z, axR[p].w);
                o.z = pack2(ayR[p].x, ayR[p].y); o.w = pack2(ayR[p].z, ayR[p].w);
                *(uint4*)&Aw[(r8 + p * 32) * 72 + ch8 * 8] = o;
            }
#pragma unroll
            for (int p = 0; p < 4; ++p) *(uint4*)&Bw[(r8 + p * 32) * 72 + ch8 * 8] = bR[p];
        }
        __syncthreads();
    }
#pragma unroll
    for (int rb = 0; rb < 2; ++rb)
#pragma unroll
        for (int cb = 0; cb < 4; ++cb) {
            int col = wc + cb * 16 + n16;
#pragma unroll
            for (int reg = 0; reg < 4; ++reg) {
                int row = m0 + wr + rb * 16 + quad * 4 + reg;
                Feat[(size_t)bz * 131072 + (size_t)row * 128 + col] = fmaxf(acc[rb][cb][reg], 0.f);
            }
        }
}

// ---------------- K7: row normalize fp32 -> bf16 ------------------------------
__global__ __launch_bounds__(64) void k_norm(const float* __restrict__ F,
                                             unsigned short* __restrict__ Nb) {
    int row = blockIdx.x, tdx = threadIdx.x;
    const float* p = F + (size_t)row * 128;
    float2 xy = *(const float2*)&p[tdx * 2];
    float sum = xy.x + xy.y;
#pragma unroll
    for (int off = 32; off; off >>= 1) sum += __shfl_xor(sum, off);
    float mu = sum * (1.f / 128.f);
    float d0 = xy.x - mu, d1 = xy.y - mu;
    float sq = d0 * d0 + d1 * d1;
#pragma unroll
    for (int off = 32; off; off >>= 1) sq += __shfl_xor(sq, off);
    float sd = sqrtf(sq * (1.f / 127.f));
    float inv = 1.f / (sd + 1e-8f);
    ((unsigned*)Nb)[(size_t)row * 64 + tdx] = pack2(d0 * inv, d1 * inv);
}

// ---------------- K8: out[b] = norm @ norm^T / 128 (bf16 MFMA) ----------------
__global__ __launch_bounds__(256) void k_corr(const unsigned short* __restrict__ Nb,
                                              float* __restrict__ Out) {
    __shared__ __align__(16) unsigned short sm[2 * 128 * 136];
    unsigned short* Ar = sm;
    unsigned short* Br = sm + 128 * 136;
    int tid = threadIdx.x;
    int bz = blockIdx.z;
    int n0 = blockIdx.x * 128, m0 = blockIdx.y * 128;
    const unsigned short* base = Nb + (size_t)bz * 131072;
    int w = tid >> 6, lane = tid & 63, n16 = lane & 15, quad = lane >> 4;
#pragma unroll
    for (int p = 0; p < 8; ++p) {
        int idx = tid + p * 256;
        int r = idx >> 4, ch = idx & 15;
        *(uint4*)&Ar[r * 136 + ch * 8] = *(const uint4*)&base[(size_t)(n0 + r) * 128 + ch * 8];
        *(uint4*)&Br[r * 136 + ch * 8] = *(const uint4*)&base[(size_t)(m0 + r) * 128 + ch * 8];
    }
    __syncthreads();
    int wr = (w >> 1) * 64, wc = (w & 1) * 64;
    f32x4 acc[4][4];
#pragma unroll
    for (int i = 0; i < 4; i++)
#pragma unroll
        for (int j = 0; j < 4; j++) acc[i][j] = (f32x4){0.f, 0.f, 0.f, 0.f};
#pragma unroll
    for (int kk = 0; kk < 4; ++kk) {
        short8 af[4], bf[4];
#pragma unroll
        for (int rb = 0; rb < 4; ++rb)
            af[rb] = *(const short8*)&Ar[(wr + rb * 16 + n16) * 136 + kk * 32 + quad * 8];
#pragma unroll
        for (int cb = 0; cb < 4; ++cb)
            bf[cb] = *(const short8*)&Br[(wc + cb * 16 + n16) * 136 + kk * 32 + quad * 8];
#pragma unroll
        for (int rb = 0; rb < 4; ++rb)
#pragma unroll
            for (int cb = 0; cb < 4; ++cb)
                acc[rb][cb] = __builtin_amdgcn_mfma_f32_16x16x32_bf16(af[rb], bf[cb], acc[rb][cb], 0, 0, 0);
    }
#pragma unroll
    for (int rb = 0; rb < 4; ++rb)
#pragma unroll
        for (int cb = 0; cb < 4; ++cb)
#pragma unroll
            for (int reg = 0; reg < 4; ++reg) {
                int row = n0 + wr + rb * 16 + quad * 4 + reg;
                int col = m0 + wc + cb * 16 + n16;
                Out[(size_t)bz * 1048576 + (size_t)row * 1024 + col] = acc[rb][cb][reg] * 0.0078125f;
            }
}

extern "C" void kernel_launch(void* const* d_in, const int* in_sizes, int n_in,
                              void* d_out, int out_size, void* d_ws, size_t ws_size,
                              hipStream_t stream) {
    const float* A_t = (const float*)d_in[0];
    const float* F_c = (const float*)d_in[1];
    const int*   t   = (const int*)d_in[2];
    const float* Wq  = (const float*)d_in[3];
    const float* bq  = (const float*)d_in[4];
    const float* Wk  = (const float*)d_in[5];
    const float* bk  = (const float*)d_in[6];
    const float* Wv  = (const float*)d_in[7];
    const float* bv  = (const float*)d_in[8];
    const float* Wo  = (const float*)d_in[9];
    const float* bo  = (const float*)d_in[10];
    const float* Wg  = (const float*)d_in[11];
    float* out = (float*)d_out;
    char* ws = (char*)d_ws;

    unsigned short* cb   = (unsigned short*)(ws);                 //  4 MB
    unsigned short* qb   = (unsigned short*)(ws + 4194304);       // 33.5 MB
    unsigned short* kbuf = (unsigned short*)(ws + 37748736);
    unsigned short* vtb  = (unsigned short*)(ws + 71303168);
    unsigned short* ctxb = (unsigned short*)(ws + 104857600);
    unsigned short* hb   = (unsigned short*)(ws + 138412032);     //  4 MB
    unsigned short* hgT  = (unsigned short*)(ws + 142606336);     //  4 MB
    float*          feat = (float*)        (ws + 146800640);      //  8 MB
    unsigned short* nb   = (unsigned short*)(ws + 155189248);     //  4 MB
    unsigned short* WqT  = (unsigned short*)(ws + 159383552);
    unsigned short* WkT  = (unsigned short*)(ws + 159645696);
    unsigned short* WvT  = (unsigned short*)(ws + 159907840);
    unsigned short* WoT  = (unsigned short*)(ws + 160169984);
    unsigned short* WgT  = (unsigned short*)(ws + 160432128);

    const float qscale = 0.08838834764831845f;   // 1/sqrt(128)

    k_prep_w<<<528, 256, 0, stream>>>(Wq, Wk, Wv, Wo, Wg, WqT, WkT, WvT, WoT, WgT);
    k_embed<<<1024, 256, 0, stream>>>(F_c, t, cb);
    k_proj_qkv<<<dim3(128, 8, 3), 256, 0, stream>>>(cb, WqT, WkT, WvT, bq, bk, bv,
                                                    qb, kbuf, vtb, qscale);
    k_attn2<<<1024, 256, 0, stream>>>(qb, kbuf, vtb, ctxb);
    k_proj_o<<<256, 256, 0, stream>>>(ctxb, WoT, bo, hb);
    k_proj<<<dim3(128, 1), 256, 0, stream>>>(hb, WgT, nullptr, hgT, 1.f, 1, 1);
    k_at_gemm<<<dim3(16, 1, 16), 256, 0, stream>>>(A_t, hgT, feat);
    k_norm<<<16384, 64, 0, stream>>>(feat, nb);
    k_corr<<<dim3(8, 8, 16), 256, 0, stream>>>(nb, out);
}